// Round 1
// 1048.308 us; speedup vs baseline: 1.1469x; 1.1469x over previous
//
#include <hip/hip_runtime.h>

#define BB 32
#define SS 512
#define DD 256
#define HHH 512
#define NHH 8
#define HDD 64
#define PFF 2048
#define LLL 2
#define NN (BB*SS)      /* 16384 tokens */
#define NMAXX 15

typedef unsigned short u16;
typedef unsigned int u32;

typedef __attribute__((ext_vector_type(8))) __bf16 bf16x8;
typedef __attribute__((ext_vector_type(4))) float f32x4;

__device__ __forceinline__ float bf2f(u16 u) {
  union { u32 i; float f; } x; x.i = ((u32)u) << 16; return x.f;
}
__device__ __forceinline__ u16 f2bf(float f) {
  union { float f; u32 i; } x; x.f = f;
  u32 r = x.i + 0x7FFFu + ((x.i >> 16) & 1u);
  return (u16)(r >> 16);
}
// flag==1: inputs/outputs are bf16; flag==0: they are float32
__device__ __forceinline__ float ldf(const void* p, size_t i, int flag) {
  return flag ? bf2f(((const u16*)p)[i]) : ((const float*)p)[i];
}
__device__ __forceinline__ void stf(void* p, size_t i, int flag, float v) {
  if (flag) ((u16*)p)[i] = f2bf(v); else ((float*)p)[i] = v;
}
// async global->LDS, 16B per lane; LDS dest must be wave-uniform base + lane*16
__device__ __forceinline__ void gld16(const u16* g, u16* l) {
  __builtin_amdgcn_global_load_lds(
      (const __attribute__((address_space(1))) u32*)g,
      (__attribute__((address_space(3))) u32*)l, 16, 0, 0);
}

// ---------------- dtype probe: ln1_g[0] == 1.0 ----------------
__global__ void k_flag(const u32* __restrict__ ones, int* __restrict__ flag) {
  *flag = (ones[0] == 0x3F800000u) ? 0 : 1;
}

// ---------------- fused convert + transpose [R,C] -> bf16 [C,R] ----------------
__global__ __launch_bounds__(256) void k_transpose_f(const void* __restrict__ in, size_t ioff,
    u16* __restrict__ out, int R, int C, const int* __restrict__ flagp) {
  __shared__ u16 tile[32][33];
  int flag = *flagp;
  int c0 = blockIdx.x * 32, r0 = blockIdx.y * 32;
  int tx = threadIdx.x, ty = threadIdx.y;  // 32 x 8
  #pragma unroll
  for (int i = 0; i < 4; ++i)
    tile[ty + i*8][tx] = f2bf(ldf(in, ioff + (size_t)(r0 + ty + i*8) * C + c0 + tx, flag));
  __syncthreads();
  #pragma unroll
  for (int i = 0; i < 4; ++i) out[(size_t)(c0 + ty + i*8) * R + r0 + tx] = tile[tx][ty + i*8];
}

// ---------------- embedding + PE + time encoding ----------------
__global__ __launch_bounds__(256) void k_embed(const int* __restrict__ src,
    const void* __restrict__ tiv, const void* __restrict__ emb,
    const void* __restrict__ tW, const void* __restrict__ tB,
    u16* __restrict__ X, const int* __restrict__ flagp) {
  int flag = *flagp;
  int n = blockIdx.x, d = threadIdx.x;
  int s = n & (SS - 1);
  int tok = src[n];
  float v = ldf(emb, (size_t)tok * DD + d, flag);
  int i2 = d & ~1;
  float freq = expf(-0.035977892078031968f * (float)i2);
  float ang = (float)s * freq;
  v += (d & 1) ? cosf(ang) : sinf(ang);
  float t = ldf(tiv, n, flag);
  v += t * ldf(tW, d, flag) + ldf(tB, d, flag);
  X[(size_t)n * DD + d] = f2bf(v);
}

// ---------------- neighbor mean aggregation ----------------
__global__ __launch_bounds__(256) void k_agg(const int* __restrict__ nidx,
    const int* __restrict__ ncnt, const u16* __restrict__ X, u16* __restrict__ AGG) {
  int n = blockIdx.x, d = threadIdx.x;
  int cnt = ncnt[n];
  float s = 0.f;
  for (int j = 0; j < cnt; ++j) {
    int m = nidx[n * NMAXX + j];
    s += bf2f(X[(size_t)m * DD + d]);
  }
  float div = (float)(cnt > 0 ? cnt : 1);
  AGG[(size_t)n * DD + d] = f2bf(s / div);
}

// ---------------- m97-style bf16 MFMA GEMM: 128x128 tile, BK=32, global_load_lds ----------------
// C[M,N] = A[M,K] @ BT[N,K]^T + bias (+res) (relu?). 4 waves, each 64x64 (4x4 MFMA accs).
__global__ __launch_bounds__(256) void k_gemm128(const u16* __restrict__ A,
    const u16* __restrict__ BT, const void* __restrict__ bias, int boff,
    const u16* __restrict__ res, u16* __restrict__ C, int N, int K, int relu,
    const int* __restrict__ flagp) {
  __shared__ __align__(16) u16 As[128 * 32];   // row-major, NO padding (global_load_lds)
  __shared__ __align__(16) u16 Bs[128 * 32];
  int n0 = blockIdx.x * 128, m0 = blockIdx.y * 128;
  int t = threadIdx.x;
  int lane = t & 63, w = t >> 6;
  int wm = (w >> 1) * 64, wn = (w & 1) * 64;
  int fr = lane & 15, fq = lane >> 4;
  int srow = t >> 2, sseg = t & 3;   // staging: 64 rows x 4 segs of 8 u16

  f32x4 acc[4][4];
  #pragma unroll
  for (int i = 0; i < 4; ++i)
    #pragma unroll
    for (int j = 0; j < 4; ++j) acc[i][j] = (f32x4){0.f, 0.f, 0.f, 0.f};

  const u16* ga = A  + (size_t)(m0 + srow) * K + sseg * 8;
  const u16* gb = BT + (size_t)(n0 + srow) * K + sseg * 8;
  u16* lA = As + srow * 32 + sseg * 8;
  u16* lB = Bs + srow * 32 + sseg * 8;
  const size_t rstride = (size_t)64 * K;

  for (int k0 = 0; k0 < K; k0 += 32) {
    gld16(ga + k0, lA);
    gld16(ga + k0 + rstride, lA + 64 * 32);
    gld16(gb + k0, lB);
    gld16(gb + k0 + rstride, lB + 64 * 32);
    __syncthreads();   // drains vmcnt (compiler emits s_waitcnt before s_barrier)
    bf16x8 af[4], bf[4];
    #pragma unroll
    for (int i = 0; i < 4; ++i) af[i] = *(const bf16x8*)&As[(wm + i * 16 + fr) * 32 + fq * 8];
    #pragma unroll
    for (int j = 0; j < 4; ++j) bf[j] = *(const bf16x8*)&Bs[(wn + j * 16 + fr) * 32 + fq * 8];
    #pragma unroll
    for (int i = 0; i < 4; ++i)
      #pragma unroll
      for (int j = 0; j < 4; ++j)
        acc[i][j] = __builtin_amdgcn_mfma_f32_16x16x32_bf16(af[i], bf[j], acc[i][j], 0, 0, 0);
    __syncthreads();   // readers done before next staging overwrites
  }

  int flag = *flagp;
  #pragma unroll
  for (int j = 0; j < 4; ++j) {
    int col = n0 + wn + j * 16 + fr;
    float bv = bias ? ldf(bias, boff + col, flag) : 0.f;
    #pragma unroll
    for (int i = 0; i < 4; ++i) {
      #pragma unroll
      for (int c = 0; c < 4; ++c) {
        int row = m0 + wm + i * 16 + fq * 4 + c;
        float v = acc[i][j][c] + bv;
        if (res) v += bf2f(res[(size_t)row * N + col]);
        if (relu) v = fmaxf(v, 0.f);
        C[(size_t)row * N + col] = f2bf(v);
      }
    }
  }
}

// ---------------- soc LayerNorm(D=256) + relu + select + x += 0.2*soc ----------------
__global__ __launch_bounds__(256) void k_ln_soc(const u16* __restrict__ socp,
    const u16* __restrict__ X, const void* __restrict__ g, const void* __restrict__ beta,
    const int* __restrict__ ncnt, const int* __restrict__ src,
    u16* __restrict__ X2, void* __restrict__ dout, const int* __restrict__ flagp) {
  __shared__ float sred[4];
  int flag = *flagp;
  int n = blockIdx.x, t = threadIdx.x;
  size_t base = (size_t)n * DD;
  float v = bf2f(socp[base + t]);
  float s = v;
  #pragma unroll
  for (int o = 32; o; o >>= 1) s += __shfl_xor(s, o, 64);
  if ((t & 63) == 0) sred[t >> 6] = s;
  __syncthreads();
  float mean = (sred[0] + sred[1] + sred[2] + sred[3]) * (1.f / DD);
  float dv = v - mean;
  float q = dv * dv;
  #pragma unroll
  for (int o = 32; o; o >>= 1) q += __shfl_xor(q, o, 64);
  __syncthreads();
  if ((t & 63) == 0) sred[t >> 6] = q;
  __syncthreads();
  float var = (sred[0] + sred[1] + sred[2] + sred[3]) * (1.f / DD);
  float rs = rsqrtf(var + 1e-5f);
  float soc = fmaxf(dv * rs * ldf(g, t, flag) + ldf(beta, t, flag), 0.f);
  float xv = bf2f(X[base + t]);
  if (ncnt[n] <= 0) soc = xv;
  if (src[n] == 0)  soc = 0.f;
  float ov = xv + 0.2f * soc;
  X2[base + t] = f2bf(ov);
  stf(dout, (size_t)NN * HHH + base + t, flag, ov);
}

// ---------------- LayerNorm(H=512) of (a+b) -> bf16 out ----------------
__global__ __launch_bounds__(256) void k_ln_add(const u16* __restrict__ a,
    const u16* __restrict__ b, const void* __restrict__ g, int goff,
    const void* __restrict__ bb, int boff, u16* __restrict__ out,
    const int* __restrict__ flagp) {
  __shared__ float sred[4];
  int flag = *flagp;
  int row = blockIdx.x, t = threadIdx.x;
  size_t base = (size_t)row * HHH;
  float v0 = bf2f(a[base + t])       + bf2f(b[base + t]);
  float v1 = bf2f(a[base + 256 + t]) + bf2f(b[base + 256 + t]);
  float s = v0 + v1;
  #pragma unroll
  for (int o = 32; o; o >>= 1) s += __shfl_xor(s, o, 64);
  if ((t & 63) == 0) sred[t >> 6] = s;
  __syncthreads();
  float mean = (sred[0] + sred[1] + sred[2] + sred[3]) * (1.f / HHH);
  float d0 = v0 - mean, d1 = v1 - mean;
  float q = d0 * d0 + d1 * d1;
  #pragma unroll
  for (int o = 32; o; o >>= 1) q += __shfl_xor(q, o, 64);
  __syncthreads();
  if ((t & 63) == 0) sred[t >> 6] = q;
  __syncthreads();
  float var = (sred[0] + sred[1] + sred[2] + sred[3]) * (1.f / HHH);
  float rs = rsqrtf(var + 1e-5f);
  out[base + t]       = f2bf(d0 * rs * ldf(g, goff + t, flag)       + ldf(bb, boff + t, flag));
  out[base + 256 + t] = f2bf(d1 * rs * ldf(g, goff + 256 + t, flag) + ldf(bb, boff + 256 + t, flag));
}

// ---------------- MFMA attention v2: one block per (head, batch) ----------------
// 256 blocks = 1/CU. K (XOR-swizzled) + V^T (XOR-swizzled) staged once in LDS.
// 8 waves; each wave owns 16 q-rows per 128-row chunk; 4 chunks cover S=512.
// P LDS round-trip is per-wave-private -> NO barriers in the main loop.
__global__ __launch_bounds__(512, 2) void k_attn_mfma(const u16* __restrict__ Q,
    const u16* __restrict__ Kb, const u16* __restrict__ Vb,
    const int* __restrict__ src, u16* __restrict__ O) {
  __shared__ __align__(16) u16 Ks[512 * 64];    // [key][d], 16B granules XOR-swizzled by (key&7)
  __shared__ __align__(16) u16 VTs[64 * 512];   // [d][key], 16B granules XOR-swizzled by (d&7)
  __shared__ __align__(16) u16 Ps[128 * 72];    // [q_local][64 keys + 8 pad], per-wave 16-row bands
  __shared__ float maskv[512];
  int h = blockIdx.x, b = blockIdx.y;
  int t = threadIdx.x;
  int w = t >> 6, lane = t & 63;
  int fr = lane & 15, fq = lane >> 4;

  maskv[t] = (src[b * SS + t] != 0) ? 1.f : 0.f;

  // --- stage K via global_load_lds with PRE-SWIZZLED source (m173 pattern) ---
  // linear LDS dest granule off=(row,g); data placed there is K[row][g ^ (row&7)]
  #pragma unroll
  for (int i = 0; i < 8; ++i) {
    int off = t + i * 512;          // 16B granule index 0..4095
    int row = off >> 3;             // key 0..511
    int gs  = (off & 7) ^ (row & 7);
    gld16(Kb + (size_t)(b * SS + row) * HHH + h * HDD + gs * 8, Ks + (size_t)off * 8);
  }
  // --- stage V transposed: thread t handles key=t; swizzle key-granule low3 by (d&7) ---
  {
    const u16* vsrc = Vb + (size_t)(b * SS + t) * HHH + h * HDD;
    int ghi = (t >> 3) & ~7, glo = (t >> 3) & 7, kw = t & 7;
    #pragma unroll
    for (int i = 0; i < 8; ++i) {
      uint4 raw = *(const uint4*)(vsrc + i * 8);
      u16 e[8]; *(uint4*)e = raw;
      #pragma unroll
      for (int jj = 0; jj < 8; ++jj) {
        int d = i * 8 + jj;
        VTs[(size_t)d * 512 + (size_t)((ghi | (glo ^ (d & 7))) * 8 + kw)] = e[jj];
      }
    }
  }
  __syncthreads();   // only barrier: staging complete (drains gld16 vmcnt + ds writes)

  for (int chunk = 0; chunk < 4; ++chunk) {
    int qb = chunk * 128 + w * 16;      // this wave's 16 q-rows
    bf16x8 qf[2];
    #pragma unroll
    for (int kc = 0; kc < 2; ++kc)
      qf[kc] = *(const bf16x8*)&Q[(size_t)(b * SS + qb + fr) * HHH + h * HDD + kc * 32 + fq * 8];

    f32x4 sacc[32];
    #pragma unroll
    for (int j = 0; j < 32; ++j) sacc[j] = (f32x4){0.f, 0.f, 0.f, 0.f};

    // QK^T: A = Q frag (rows=q), B = K frag (rows=key) from swizzled LDS
    #pragma unroll
    for (int kt = 0; kt < 32; ++kt) {
      int row = kt * 16 + fr;           // row&7 == fr&7
      #pragma unroll
      for (int kc = 0; kc < 2; ++kc) {
        bf16x8 kf = *(const bf16x8*)&Ks[(size_t)row * 64 +
            (size_t)(((kc * 4 + fq) ^ (fr & 7)) * 8)];
        sacc[kt] = __builtin_amdgcn_mfma_f32_16x16x32_bf16(qf[kc], kf, sacc[kt], 0, 0, 0);
      }
    }

    // scale + key mask (broadcast LDS reads, uniform over fq)
    #pragma unroll
    for (int j = 0; j < 32; ++j) {
      float mv = maskv[j * 16 + fr];
      #pragma unroll
      for (int c = 0; c < 4; ++c) {
        float v = sacc[j][c] * 0.125f;
        sacc[j][c] = (mv != 0.f) ? v : -1e10f;
      }
    }
    // softmax per q-row (q = fq*4+c): reduce over 32 tiles in-lane + fr lanes (xor 1,2,4,8)
    #pragma unroll
    for (int c = 0; c < 4; ++c) {
      float m = -3.0e38f;
      #pragma unroll
      for (int j = 0; j < 32; ++j) m = fmaxf(m, sacc[j][c]);
      #pragma unroll
      for (int o = 1; o < 16; o <<= 1) m = fmaxf(m, __shfl_xor(m, o, 64));
      float s = 0.f;
      #pragma unroll
      for (int j = 0; j < 32; ++j) { float e = __expf(sacc[j][c] - m); sacc[j][c] = e; s += e; }
      #pragma unroll
      for (int o = 1; o < 16; o <<= 1) s += __shfl_xor(s, o, 64);
      float inv = 1.f / s;
      #pragma unroll
      for (int j = 0; j < 32; ++j) sacc[j][c] *= inv;
    }

    // PV: per 64-key segment, round-trip P through this wave's private Ps band.
    // Within-wave DS ordering (lgkmcnt) handles write->read and read->overwrite; no barriers.
    f32x4 oacc[4];
    #pragma unroll
    for (int n = 0; n < 4; ++n) oacc[n] = (f32x4){0.f, 0.f, 0.f, 0.f};

    #pragma unroll
    for (int seg = 0; seg < 8; ++seg) {
      #pragma unroll
      for (int tt = 0; tt < 4; ++tt)
        #pragma unroll
        for (int c = 0; c < 4; ++c)
          Ps[(size_t)(w * 16 + fq * 4 + c) * 72 + tt * 16 + fr] = f2bf(sacc[seg * 4 + tt][c]);
      #pragma unroll
      for (int kc = 0; kc < 2; ++kc) {
        bf16x8 pa = *(const bf16x8*)&Ps[(size_t)(w * 16 + fr) * 72 + kc * 32 + fq * 8];
        #pragma unroll
        for (int nt = 0; nt < 4; ++nt) {
          bf16x8 bv = *(const bf16x8*)&VTs[(size_t)(nt * 16 + fr) * 512 +
              (size_t)((seg * 8 + ((kc * 4 + fq) ^ (fr & 7))) * 8)];
          oacc[nt] = __builtin_amdgcn_mfma_f32_16x16x32_bf16(pa, bv, oacc[nt], 0, 0, 0);
        }
      }
    }

    #pragma unroll
    for (int nt = 0; nt < 4; ++nt)
      #pragma unroll
      for (int c = 0; c < 4; ++c)
        O[(size_t)(b * SS + qb + fq * 4 + c) * HHH + h * HDD + nt * 16 + fr] = f2bf(oacc[nt][c]);
  }
}

// ---------------- final h copy: bf16 internal -> output dtype ----------------
__global__ __launch_bounds__(256) void k_out(const u16* __restrict__ Hb,
    void* __restrict__ out, const int* __restrict__ flagp) {
  int flag = *flagp;
  size_t i = ((size_t)blockIdx.x * 256 + threadIdx.x) * 4;
  if (flag) {
    *(uint2*)((u16*)out + i) = *(const uint2*)(Hb + i);
  } else {
    float4 v;
    v.x = bf2f(Hb[i]); v.y = bf2f(Hb[i+1]); v.z = bf2f(Hb[i+2]); v.w = bf2f(Hb[i+3]);
    *(float4*)((float*)out + i) = v;
  }
}

extern "C" void kernel_launch(void* const* d_in, const int* in_sizes, int n_in,
                              void* d_out, int out_size, void* d_ws, size_t ws_size,
                              hipStream_t stream) {
  (void)in_sizes; (void)n_in; (void)out_size; (void)ws_size;
  const int* src    = (const int*)d_in[0];
  const int* nidx   = (const int*)d_in[2];
  const int* ncnt   = (const int*)d_in[3];
  const void* tiv   = d_in[4];
  const void* emb   = d_in[5];
  const void* tW    = d_in[6];
  const void* tB    = d_in[7];
  const void* socW  = d_in[8];
  const void* socb  = d_in[9];
  const void* socg  = d_in[10];
  const void* socbe = d_in[11];
  const void* projW = d_in[12];
  const void* projb = d_in[13];
  const void* Wq    = d_in[14];
  const void* bq    = d_in[15];
  const void* Wk    = d_in[16];
  const void* bk    = d_in[17];
  const void* Wv    = d_in[18];
  const void* bv    = d_in[19];
  const void* Wo    = d_in[20];
  const void* bo    = d_in[21];
  const void* ln1g  = d_in[22];
  const void* ln1b  = d_in[23];
  const void* W1    = d_in[24];
  const void* b1    = d_in[25];
  const void* W2    = d_in[26];
  const void* b2    = d_in[27];
  const void* ln2g  = d_in[28];
  const void* ln2b  = d_in[29];

  const size_t NHS = (size_t)NN * HHH;
  u16* ws = (u16*)d_ws;
  u16* socWT  = ws;
  u16* projWT = socWT + (size_t)DD * DD;
  u16* WqT    = projWT + (size_t)DD * HHH;
  u16* WkT    = WqT + (size_t)LLL * HHH * HHH;
  u16* WvT    = WkT + (size_t)LLL * HHH * HHH;
  u16* WoT    = WvT + (size_t)LLL * HHH * HHH;
  u16* W1T    = WoT + (size_t)LLL * HHH * HHH;
  u16* W2T    = W1T + (size_t)LLL * HHH * PFF;
  u16* Hb     = W2T + (size_t)LLL * HHH * PFF;
  u16* P1     = Hb + NHS;
  u16* P2     = P1 + NHS;
  u16* P3     = P2 + NHS;
  int* flagp  = (int*)(P3 + NHS);
  u16* X    = P1;
  u16* AGG  = P2;
  u16* SOCP = P3;
  u16* X2   = P2;
  u16* Ob   = (u16*)d_out;
  u16* FFM  = P2;

  k_flag<<<1, 1, 0, stream>>>((const u32*)ln1g, flagp);

  dim3 tb(32, 8);
  k_transpose_f<<<dim3(DD / 32, DD / 32), tb, 0, stream>>>(socW, 0, socWT, DD, DD, flagp);
  k_transpose_f<<<dim3(HHH / 32, DD / 32), tb, 0, stream>>>(projW, 0, projWT, DD, HHH, flagp);
  for (int l = 0; l < LLL; ++l) {
    size_t oHH = (size_t)l * HHH * HHH, oHP = (size_t)l * HHH * PFF;
    k_transpose_f<<<dim3(HHH / 32, HHH / 32), tb, 0, stream>>>(Wq, oHH, WqT + oHH, HHH, HHH, flagp);
    k_transpose_f<<<dim3(HHH / 32, HHH / 32), tb, 0, stream>>>(Wk, oHH, WkT + oHH, HHH, HHH, flagp);
    k_transpose_f<<<dim3(HHH / 32, HHH / 32), tb, 0, stream>>>(Wv, oHH, WvT + oHH, HHH, HHH, flagp);
    k_transpose_f<<<dim3(HHH / 32, HHH / 32), tb, 0, stream>>>(Wo, oHH, WoT + oHH, HHH, HHH, flagp);
    k_transpose_f<<<dim3(PFF / 32, HHH / 32), tb, 0, stream>>>(W1, oHP, W1T + oHP, HHH, PFF, flagp);
    k_transpose_f<<<dim3(HHH / 32, PFF / 32), tb, 0, stream>>>(W2, oHP, W2T + oHP, PFF, HHH, flagp);
  }

  k_embed<<<NN, 256, 0, stream>>>(src, tiv, emb, tW, tB, X, flagp);
  k_agg<<<NN, 256, 0, stream>>>(nidx, ncnt, X, AGG);
  k_gemm128<<<dim3(DD / 128, NN / 128), 256, 0, stream>>>(AGG, socWT, socb, 0, X, SOCP, DD, DD, 0, flagp);
  k_ln_soc<<<NN, 256, 0, stream>>>(SOCP, X, socg, socbe, ncnt, src, X2, d_out, flagp);
  k_gemm128<<<dim3(HHH / 128, NN / 128), 256, 0, stream>>>(X2, projWT, projb, 0, (const u16*)nullptr, Hb, HHH, DD, 0, flagp);

  for (int l = 0; l < LLL; ++l) {
    size_t oHH = (size_t)l * HHH * HHH, oHP = (size_t)l * HHH * PFF;
    k_gemm128<<<dim3(4, 128), 256, 0, stream>>>(Hb, WqT + oHH, bq, l * HHH, (const u16*)nullptr, P1, HHH, HHH, 0, flagp);
    k_gemm128<<<dim3(4, 128), 256, 0, stream>>>(Hb, WkT + oHH, bk, l * HHH, (const u16*)nullptr, P2, HHH, HHH, 0, flagp);
    k_gemm128<<<dim3(4, 128), 256, 0, stream>>>(Hb, WvT + oHH, bv, l * HHH, (const u16*)nullptr, P3, HHH, HHH, 0, flagp);
    k_attn_mfma<<<dim3(NHH, BB), 512, 0, stream>>>(P1, P2, P3, src, Ob);
    k_gemm128<<<dim3(4, 128), 256, 0, stream>>>(Ob, WoT + oHH, bo, l * HHH, (const u16*)nullptr, P1, HHH, HHH, 0, flagp);
    k_ln_add<<<NN, 256, 0, stream>>>(Hb, P1, ln1g, l * HHH, ln1b, l * HHH, Hb, flagp);
    for (int c = 0; c < 2; ++c) {
      const u16* Asrc = Hb + (size_t)c * 8192 * HHH;
      u16* Cdst = P1 + (size_t)c * 8192 * HHH;
      k_gemm128<<<dim3(PFF / 128, 8192 / 128), 256, 0, stream>>>(Asrc, W1T + oHP, b1, l * PFF, (const u16*)nullptr, FFM, PFF, HHH, 1, flagp);
      k_gemm128<<<dim3(HHH / 128, 8192 / 128), 256, 0, stream>>>(FFM, W2T + oHP, b2, l * HHH, (const u16*)nullptr, Cdst, HHH, PFF, 0, flagp);
    }
    k_ln_add<<<NN, 256, 0, stream>>>(Hb, P1, ln2g, l * HHH, ln2b, l * HHH, Hb, flagp);
  }
  k_out<<<dim3((unsigned)(NHS / 4 / 256)), 256, 0, stream>>>(Hb, d_out, flagp);
}

// Round 4
// 900.666 us; speedup vs baseline: 1.3349x; 1.1639x over previous
//
#include <hip/hip_runtime.h>

#define BB 32
#define SS 512
#define DD 256
#define HHH 512
#define NHH 8
#define HDD 64
#define PFF 2048
#define LLL 2
#define NN (BB*SS)      /* 16384 tokens */
#define NMAXX 15

typedef unsigned short u16;
typedef unsigned int u32;

typedef __attribute__((ext_vector_type(8))) __bf16 bf16x8;
typedef __attribute__((ext_vector_type(4))) float f32x4;

__device__ __forceinline__ float bf2f(u16 u) {
  union { u32 i; float f; } x; x.i = ((u32)u) << 16; return x.f;
}
__device__ __forceinline__ u16 f2bf(float f) {
  union { float f; u32 i; } x; x.f = f;
  u32 r = x.i + 0x7FFFu + ((x.i >> 16) & 1u);
  return (u16)(r >> 16);
}
// flag==1: inputs/outputs are bf16; flag==0: they are float32
__device__ __forceinline__ float ldf(const void* p, size_t i, int flag) {
  return flag ? bf2f(((const u16*)p)[i]) : ((const float*)p)[i];
}
__device__ __forceinline__ void stf(void* p, size_t i, int flag, float v) {
  if (flag) ((u16*)p)[i] = f2bf(v); else ((float*)p)[i] = v;
}
// async global->LDS, 16B per lane; LDS dest must be wave-uniform base + lane*16
__device__ __forceinline__ void gld16(const u16* g, u16* l) {
  __builtin_amdgcn_global_load_lds(
      (const __attribute__((address_space(1))) u32*)g,
      (__attribute__((address_space(3))) u32*)l, 16, 0, 0);
}

// ---------------- dtype probe: ln1_g[0] == 1.0 ----------------
__global__ void k_flag(const u32* __restrict__ ones, int* __restrict__ flag) {
  *flag = (ones[0] == 0x3F800000u) ? 0 : 1;
}

// ---------------- fused convert + transpose [R,C] -> bf16 [C,R] ----------------
__global__ __launch_bounds__(256) void k_transpose_f(const void* __restrict__ in, size_t ioff,
    u16* __restrict__ out, int R, int C, const int* __restrict__ flagp) {
  __shared__ u16 tile[32][33];
  int flag = *flagp;
  int c0 = blockIdx.x * 32, r0 = blockIdx.y * 32;
  int tx = threadIdx.x, ty = threadIdx.y;  // 32 x 8
  #pragma unroll
  for (int i = 0; i < 4; ++i)
    tile[ty + i*8][tx] = f2bf(ldf(in, ioff + (size_t)(r0 + ty + i*8) * C + c0 + tx, flag));
  __syncthreads();
  #pragma unroll
  for (int i = 0; i < 4; ++i) out[(size_t)(c0 + ty + i*8) * R + r0 + tx] = tile[tx][ty + i*8];
}

// ---------------- pack all biases to bf16 ----------------
// layout: [projb 512][per-layer: bq,bk,bv (1536) | b1 (2048) | bo (512) | b2 (512)]
__global__ __launch_bounds__(256) void k_packb(const void* __restrict__ projb,
    const void* __restrict__ bq, const void* __restrict__ bk, const void* __restrict__ bv,
    const void* __restrict__ b1, const void* __restrict__ bo, const void* __restrict__ b2,
    u16* __restrict__ out, const int* __restrict__ flagp) {
  int flag = *flagp;
  int i = blockIdx.x * 256 + threadIdx.x;
  int tot = 512 + LLL * 4608;
  if (i >= tot) return;
  float v;
  if (i < 512) v = ldf(projb, i, flag);
  else {
    int j = i - 512, l = j / 4608, r = j % 4608;
    if      (r < 512)  v = ldf(bq, (size_t)l * HHH + r, flag);
    else if (r < 1024) v = ldf(bk, (size_t)l * HHH + r - 512, flag);
    else if (r < 1536) v = ldf(bv, (size_t)l * HHH + r - 1024, flag);
    else if (r < 3584) v = ldf(b1, (size_t)l * PFF + r - 1536, flag);
    else if (r < 4096) v = ldf(bo, (size_t)l * HHH + r - 3584, flag);
    else               v = ldf(b2, (size_t)l * HHH + r - 4096, flag);
  }
  out[i] = f2bf(v);
}

// ---------------- embedding + PE + time encoding ----------------
__global__ __launch_bounds__(256) void k_embed(const int* __restrict__ src,
    const void* __restrict__ tiv, const void* __restrict__ emb,
    const void* __restrict__ tW, const void* __restrict__ tB,
    u16* __restrict__ X, const int* __restrict__ flagp) {
  int flag = *flagp;
  int n = blockIdx.x, d = threadIdx.x;
  int s = n & (SS - 1);
  int tok = src[n];
  float v = ldf(emb, (size_t)tok * DD + d, flag);
  int i2 = d & ~1;
  float freq = expf(-0.035977892078031968f * (float)i2);
  float ang = (float)s * freq;
  v += (d & 1) ? cosf(ang) : sinf(ang);
  float t = ldf(tiv, n, flag);
  v += t * ldf(tW, d, flag) + ldf(tB, d, flag);
  X[(size_t)n * DD + d] = f2bf(v);
}

// ---------------- neighbor mean aggregation ----------------
__global__ __launch_bounds__(256) void k_agg(const int* __restrict__ nidx,
    const int* __restrict__ ncnt, const u16* __restrict__ X, u16* __restrict__ AGG) {
  int n = blockIdx.x, d = threadIdx.x;
  int cnt = ncnt[n];
  float s = 0.f;
  for (int j = 0; j < cnt; ++j) {
    int m = nidx[n * NMAXX + j];
    s += bf2f(X[(size_t)m * DD + d]);
  }
  float div = (float)(cnt > 0 ? cnt : 1);
  AGG[(size_t)n * DD + d] = f2bf(s / div);
}

// ---------------- m97-style bf16 MFMA GEMM (kept for soc, N=256) ----------------
__global__ __launch_bounds__(256) void k_gemm128(const u16* __restrict__ A,
    const u16* __restrict__ BT, const void* __restrict__ bias, int boff,
    const u16* __restrict__ res, u16* __restrict__ C, int N, int K, int relu,
    const int* __restrict__ flagp) {
  __shared__ __align__(16) u16 As[128 * 32];
  __shared__ __align__(16) u16 Bs[128 * 32];
  int n0 = blockIdx.x * 128, m0 = blockIdx.y * 128;
  int t = threadIdx.x;
  int lane = t & 63, w = t >> 6;
  int wm = (w >> 1) * 64, wn = (w & 1) * 64;
  int fr = lane & 15, fq = lane >> 4;
  int srow = t >> 2, sseg = t & 3;

  f32x4 acc[4][4];
  #pragma unroll
  for (int i = 0; i < 4; ++i)
    #pragma unroll
    for (int j = 0; j < 4; ++j) acc[i][j] = (f32x4){0.f, 0.f, 0.f, 0.f};

  const u16* ga = A  + (size_t)(m0 + srow) * K + sseg * 8;
  const u16* gb = BT + (size_t)(n0 + srow) * K + sseg * 8;
  u16* lA = As + srow * 32 + sseg * 8;
  u16* lB = Bs + srow * 32 + sseg * 8;
  const size_t rstride = (size_t)64 * K;

  for (int k0 = 0; k0 < K; k0 += 32) {
    gld16(ga + k0, lA);
    gld16(ga + k0 + rstride, lA + 64 * 32);
    gld16(gb + k0, lB);
    gld16(gb + k0 + rstride, lB + 64 * 32);
    __syncthreads();
    bf16x8 af[4], bf[4];
    #pragma unroll
    for (int i = 0; i < 4; ++i) af[i] = *(const bf16x8*)&As[(wm + i * 16 + fr) * 32 + fq * 8];
    #pragma unroll
    for (int j = 0; j < 4; ++j) bf[j] = *(const bf16x8*)&Bs[(wn + j * 16 + fr) * 32 + fq * 8];
    #pragma unroll
    for (int i = 0; i < 4; ++i)
      #pragma unroll
      for (int j = 0; j < 4; ++j)
        acc[i][j] = __builtin_amdgcn_mfma_f32_16x16x32_bf16(af[i], bf[j], acc[i][j], 0, 0, 0);
    __syncthreads();
  }

  int flag = *flagp;
  #pragma unroll
  for (int j = 0; j < 4; ++j) {
    int col = n0 + wn + j * 16 + fr;
    float bv = bias ? ldf(bias, boff + col, flag) : 0.f;
    #pragma unroll
    for (int i = 0; i < 4; ++i) {
      #pragma unroll
      for (int c = 0; c < 4; ++c) {
        int row = m0 + wm + i * 16 + fq * 4 + c;
        float v = acc[i][j][c] + bv;
        if (res) v += bf2f(res[(size_t)row * N + col]);
        if (relu) v = fmaxf(v, 0.f);
        C[(size_t)row * N + col] = f2bf(v);
      }
    }
  }
}

// ---------------- pipelined 256-row-tile GEMM: BM=256, BN=64*NBF, BK=32 ----------------
// 3 LDS stages; stage tile T+2 while computing tile T; counted vmcnt (T4); XOR-swizzled
// LDS granules (T2, both sides); setprio around MFMA clusters (T5); XCD block swizzle (T1).
// Boundary drains lgkmcnt(0): ds_read waits are dependency-anchored, not barrier-anchored
// (rule #18); stage (T+2)%3 being overwritten is the one read in iter T-1.
template<int NBF>
__global__ __launch_bounds__(512, 2) void k_gemm256(const u16* __restrict__ A,
    const u16* __restrict__ BT, const u16* __restrict__ bias,
    u16* __restrict__ C, int N, int K, int relu, int nbx) {
  constexpr int AG = 1024;                 // A 16B-granules per stage: 256 rows x 4
  constexpr int BG = NBF * 256;            // B granules per stage: 64*NBF rows x 4
  constexpr int STRIDE = (AG + BG) * 8;    // u16 per stage
  constexpr int LPT = 2 + BG / 512;        // gld16 per thread per tile
  __shared__ __align__(16) u16 S[3 * STRIDE];

  int nwg = gridDim.x;
  int id = blockIdx.x;
  int wg = ((nwg & 7) == 0) ? ((id & 7) * (nwg >> 3) + (id >> 3)) : id;
  int bx = wg % nbx, by = wg / nbx;
  int m0 = by * 256, n0 = bx * (64 * NBF);

  int t = threadIdx.x;
  int w = t >> 6, lane = t & 63;
  int fr = lane & 15, fq = lane >> 4;
  int wm = (w >> 2) * 128, wn = (w & 3) * (16 * NBF);
  // frag-read granule: fq ^ (row&3) ^ ((row>>2)&3), row = base16 + fr -> lane-constant
  int gsw8 = (fq ^ (fr & 3) ^ ((fr >> 2) & 3)) * 8;

  // staging: thread t covers granule t (and t+512): row = g>>2, seg = g&3
  int arow = t >> 2, aseg = t & 3;
  int asw = aseg ^ (arow & 3) ^ ((arow >> 2) & 3);   // row+128 keeps same swizzle
  const u16* gA  = A  + (size_t)(m0 + arow) * K + asw * 8;
  const u16* gA2 = gA + (size_t)128 * K;
  const u16* gB  = BT + (size_t)(n0 + arow) * K + asw * 8;
  const u16* gB2 = gB + (size_t)128 * K;             // used when NBF==4

  f32x4 acc[8][NBF];
  #pragma unroll
  for (int i = 0; i < 8; ++i)
    #pragma unroll
    for (int j = 0; j < NBF; ++j) acc[i][j] = (f32x4){0.f, 0.f, 0.f, 0.f};

  int NT = K >> 5;

  // prologue: stage tiles 0,1; wait until tile 0 landed (LPT outstanding = tile 1)
  #pragma unroll
  for (int p = 0; p < 2; ++p) {
    gld16(gA  + p * 32, S + p * STRIDE + t * 8);
    gld16(gA2 + p * 32, S + p * STRIDE + (t + 512) * 8);
    gld16(gB  + p * 32, S + p * STRIDE + AG * 8 + t * 8);
    if constexpr (NBF == 4)
      gld16(gB2 + p * 32, S + p * STRIDE + AG * 8 + (t + 512) * 8);
  }
  asm volatile("s_waitcnt vmcnt(%0)" :: "n"(LPT) : "memory");
  __builtin_amdgcn_s_barrier();
  __builtin_amdgcn_sched_barrier(0);

  for (int T = 0; T < NT; ++T) {
    const u16* Sa = S + (T % 3) * STRIDE;
    const u16* Sb = Sa + AG * 8;
    u16* Sn = S + ((T + 2) % 3) * STRIDE;
    int kn = (T + 2) * 32;
    bool st = (T + 2) < NT;

    // phase a: read A-half0 + B frags, stage next A-tile, MFMA rows 0..63
    bf16x8 af[4], bf[NBF];
    #pragma unroll
    for (int i = 0; i < 4; ++i) af[i] = *(const bf16x8*)&Sa[(wm + i * 16 + fr) * 32 + gsw8];
    #pragma unroll
    for (int j = 0; j < NBF; ++j) bf[j] = *(const bf16x8*)&Sb[(wn + j * 16 + fr) * 32 + gsw8];
    if (st) {
      gld16(gA  + kn, Sn + t * 8);
      gld16(gA2 + kn, Sn + (t + 512) * 8);
    }
    __builtin_amdgcn_s_setprio(1);
    #pragma unroll
    for (int i = 0; i < 4; ++i)
      #pragma unroll
      for (int j = 0; j < NBF; ++j)
        acc[i][j] = __builtin_amdgcn_mfma_f32_16x16x32_bf16(af[i], bf[j], acc[i][j], 0, 0, 0);
    __builtin_amdgcn_s_setprio(0);

    // phase b: read A-half1, stage next B-tile, MFMA rows 64..127
    bf16x8 ag[4];
    #pragma unroll
    for (int i = 0; i < 4; ++i) ag[i] = *(const bf16x8*)&Sa[(wm + 64 + i * 16 + fr) * 32 + gsw8];
    if (st) {
      gld16(gB + kn, Sn + AG * 8 + t * 8);
      if constexpr (NBF == 4)
        gld16(gB2 + kn, Sn + AG * 8 + (t + 512) * 8);
    }
    __builtin_amdgcn_s_setprio(1);
    #pragma unroll
    for (int i = 0; i < 4; ++i)
      #pragma unroll
      for (int j = 0; j < NBF; ++j)
        acc[4 + i][j] = __builtin_amdgcn_mfma_f32_16x16x32_bf16(ag[i], bf[j], acc[4 + i][j], 0, 0, 0);
    __builtin_amdgcn_s_setprio(0);

    // tile boundary: drain this wave's ds_reads + counted vmcnt, then barrier.
    if (st) { asm volatile("s_waitcnt vmcnt(%0) lgkmcnt(0)" :: "n"(LPT) : "memory"); }
    else    { asm volatile("s_waitcnt vmcnt(0) lgkmcnt(0)" ::: "memory"); }
    __builtin_amdgcn_s_barrier();
    __builtin_amdgcn_sched_barrier(0);
  }

  #pragma unroll
  for (int j = 0; j < NBF; ++j) {
    int col = n0 + wn + j * 16 + fr;
    float bv = bf2f(bias[col]);
    #pragma unroll
    for (int i = 0; i < 8; ++i) {
      #pragma unroll
      for (int c = 0; c < 4; ++c) {
        int row = m0 + wm + i * 16 + fq * 4 + c;
        float v = acc[i][j][c] + bv;
        if (relu) v = fmaxf(v, 0.f);
        C[(size_t)row * N + col] = f2bf(v);
      }
    }
  }
}

// ---------------- soc LayerNorm(D=256) + relu + select + x += 0.2*soc ----------------
__global__ __launch_bounds__(256) void k_ln_soc(const u16* __restrict__ socp,
    const u16* __restrict__ X, const void* __restrict__ g, const void* __restrict__ beta,
    const int* __restrict__ ncnt, const int* __restrict__ src,
    u16* __restrict__ X2, void* __restrict__ dout, const int* __restrict__ flagp) {
  __shared__ float sred[4];
  int flag = *flagp;
  int n = blockIdx.x, t = threadIdx.x;
  size_t base = (size_t)n * DD;
  float v = bf2f(socp[base + t]);
  float s = v;
  #pragma unroll
  for (int o = 32; o; o >>= 1) s += __shfl_xor(s, o, 64);
  if ((t & 63) == 0) sred[t >> 6] = s;
  __syncthreads();
  float mean = (sred[0] + sred[1] + sred[2] + sred[3]) * (1.f / DD);
  float dv = v - mean;
  float q = dv * dv;
  #pragma unroll
  for (int o = 32; o; o >>= 1) q += __shfl_xor(q, o, 64);
  __syncthreads();
  if ((t & 63) == 0) sred[t >> 6] = q;
  __syncthreads();
  float var = (sred[0] + sred[1] + sred[2] + sred[3]) * (1.f / DD);
  float rs = rsqrtf(var + 1e-5f);
  float soc = fmaxf(dv * rs * ldf(g, t, flag) + ldf(beta, t, flag), 0.f);
  float xv = bf2f(X[base + t]);
  if (ncnt[n] <= 0) soc = xv;
  if (src[n] == 0)  soc = 0.f;
  float ov = xv + 0.2f * soc;
  X2[base + t] = f2bf(ov);
  stf(dout, (size_t)NN * HHH + base + t, flag, ov);
}

// ---------------- LayerNorm(H=512) of (a+b) -> bf16 out ----------------
__global__ __launch_bounds__(256) void k_ln_add(const u16* __restrict__ a,
    const u16* __restrict__ b, const void* __restrict__ g, int goff,
    const void* __restrict__ bb, int boff, u16* __restrict__ out,
    const int* __restrict__ flagp) {
  __shared__ float sred[4];
  int flag = *flagp;
  int row = blockIdx.x, t = threadIdx.x;
  size_t base = (size_t)row * HHH;
  float v0 = bf2f(a[base + t])       + bf2f(b[base + t]);
  float v1 = bf2f(a[base + 256 + t]) + bf2f(b[base + 256 + t]);
  float s = v0 + v1;
  #pragma unroll
  for (int o = 32; o; o >>= 1) s += __shfl_xor(s, o, 64);
  if ((t & 63) == 0) sred[t >> 6] = s;
  __syncthreads();
  float mean = (sred[0] + sred[1] + sred[2] + sred[3]) * (1.f / HHH);
  float d0 = v0 - mean, d1 = v1 - mean;
  float q = d0 * d0 + d1 * d1;
  #pragma unroll
  for (int o = 32; o; o >>= 1) q += __shfl_xor(q, o, 64);
  __syncthreads();
  if ((t & 63) == 0) sred[t >> 6] = q;
  __syncthreads();
  float var = (sred[0] + sred[1] + sred[2] + sred[3]) * (1.f / HHH);
  float rs = rsqrtf(var + 1e-5f);
  out[base + t]       = f2bf(d0 * rs * ldf(g, goff + t, flag)       + ldf(bb, boff + t, flag));
  out[base + 256 + t] = f2bf(d1 * rs * ldf(g, goff + 256 + t, flag) + ldf(bb, boff + 256 + t, flag));
}

// ---------------- MFMA attention: one block per (head, batch); Q/K/V strided (ld) ----------------
__global__ __launch_bounds__(512, 2) void k_attn_mfma(const u16* __restrict__ Q,
    const u16* __restrict__ Kb, const u16* __restrict__ Vb, int ld,
    const int* __restrict__ src, u16* __restrict__ O) {
  __shared__ __align__(16) u16 Ks[512 * 64];
  __shared__ __align__(16) u16 VTs[64 * 512];
  __shared__ __align__(16) u16 Ps[128 * 72];
  __shared__ float maskv[512];
  int h = blockIdx.x, b = blockIdx.y;
  int t = threadIdx.x;
  int w = t >> 6, lane = t & 63;
  int fr = lane & 15, fq = lane >> 4;

  maskv[t] = (src[b * SS + t] != 0) ? 1.f : 0.f;

  #pragma unroll
  for (int i = 0; i < 8; ++i) {
    int off = t + i * 512;
    int row = off >> 3;
    int gs  = (off & 7) ^ (row & 7);
    gld16(Kb + (size_t)(b * SS + row) * ld + h * HDD + gs * 8, Ks + (size_t)off * 8);
  }
  {
    const u16* vsrc = Vb + (size_t)(b * SS + t) * ld + h * HDD;
    int ghi = (t >> 3) & ~7, glo = (t >> 3) & 7, kw = t & 7;
    #pragma unroll
    for (int i = 0; i < 8; ++i) {
      uint4 raw = *(const uint4*)(vsrc + i * 8);
      u16 e[8]; *(uint4*)e = raw;
      #pragma unroll
      for (int jj = 0; jj < 8; ++jj) {
        int d = i * 8 + jj;
        VTs[(size_t)d * 512 + (size_t)((ghi | (glo ^ (d & 7))) * 8 + kw)] = e[jj];
      }
    }
  }
  __syncthreads();

  for (int chunk = 0; chunk < 4; ++chunk) {
    int qb = chunk * 128 + w * 16;
    bf16x8 qf[2];
    #pragma unroll
    for (int kc = 0; kc < 2; ++kc)
      qf[kc] = *(const bf16x8*)&Q[(size_t)(b * SS + qb + fr) * ld + h * HDD + kc * 32 + fq * 8];

    f32x4 sacc[32];
    #pragma unroll
    for (int j = 0; j < 32; ++j) sacc[j] = (f32x4){0.f, 0.f, 0.f, 0.f};

    #pragma unroll
    for (int kt = 0; kt < 32; ++kt) {
      int row = kt * 16 + fr;
      #pragma unroll
      for (int kc = 0; kc < 2; ++kc) {
        bf16x8 kf = *(const bf16x8*)&Ks[(size_t)row * 64 +
            (size_t)(((kc * 4 + fq) ^ (fr & 7)) * 8)];
        sacc[kt] = __builtin_amdgcn_mfma_f32_16x16x32_bf16(qf[kc], kf, sacc[kt], 0, 0, 0);
      }
    }

    #pragma unroll
    for (int j = 0; j < 32; ++j) {
      float mv = maskv[j * 16 + fr];
      #pragma unroll
      for (int c = 0; c < 4; ++c) {
        float v = sacc[j][c] * 0.125f;
        sacc[j][c] = (mv != 0.f) ? v : -1e10f;
      }
    }
    #pragma unroll
    for (int c = 0; c < 4; ++c) {
      float m = -3.0e38f;
      #pragma unroll
      for (int j = 0; j < 32; ++j) m = fmaxf(m, sacc[j][c]);
      #pragma unroll
      for (int o = 1; o < 16; o <<= 1) m = fmaxf(m, __shfl_xor(m, o, 64));
      float s = 0.f;
      #pragma unroll
      for (int j = 0; j < 32; ++j) { float e = __expf(sacc[j][c] - m); sacc[j][c] = e; s += e; }
      #pragma unroll
      for (int o = 1; o < 16; o <<= 1) s += __shfl_xor(s, o, 64);
      float inv = 1.f / s;
      #pragma unroll
      for (int j = 0; j < 32; ++j) sacc[j][c] *= inv;
    }

    f32x4 oacc[4];
    #pragma unroll
    for (int n = 0; n < 4; ++n) oacc[n] = (f32x4){0.f, 0.f, 0.f, 0.f};

    #pragma unroll
    for (int seg = 0; seg < 8; ++seg) {
      #pragma unroll
      for (int tt = 0; tt < 4; ++tt)
        #pragma unroll
        for (int c = 0; c < 4; ++c)
          Ps[(size_t)(w * 16 + fq * 4 + c) * 72 + tt * 16 + fr] = f2bf(sacc[seg * 4 + tt][c]);
      #pragma unroll
      for (int kc = 0; kc < 2; ++kc) {
        bf16x8 pa = *(const bf16x8*)&Ps[(size_t)(w * 16 + fr) * 72 + kc * 32 + fq * 8];
        #pragma unroll
        for (int nt = 0; nt < 4; ++nt) {
          bf16x8 bv = *(const bf16x8*)&VTs[(size_t)(nt * 16 + fr) * 512 +
              (size_t)((seg * 8 + ((kc * 4 + fq) ^ (fr & 7))) * 8)];
          oacc[nt] = __builtin_amdgcn_mfma_f32_16x16x32_bf16(pa, bv, oacc[nt], 0, 0, 0);
        }
      }
    }

    #pragma unroll
    for (int nt = 0; nt < 4; ++nt)
      #pragma unroll
      for (int c = 0; c < 4; ++c)
        O[(size_t)(b * SS + qb + fq * 4 + c) * HHH + h * HDD + nt * 16 + fr] = f2bf(oacc[nt][c]);
  }
}

// ---------------- final h copy: bf16 internal -> output dtype ----------------
__global__ __launch_bounds__(256) void k_out(const u16* __restrict__ Hb,
    void* __restrict__ out, const int* __restrict__ flagp) {
  int flag = *flagp;
  size_t i = ((size_t)blockIdx.x * 256 + threadIdx.x) * 4;
  if (flag) {
    *(uint2*)((u16*)out + i) = *(const uint2*)(Hb + i);
  } else {
    float4 v;
    v.x = bf2f(Hb[i]); v.y = bf2f(Hb[i+1]); v.z = bf2f(Hb[i+2]); v.w = bf2f(Hb[i+3]);
    *(float4*)((float*)out + i) = v;
  }
}

extern "C" void kernel_launch(void* const* d_in, const int* in_sizes, int n_in,
                              void* d_out, int out_size, void* d_ws, size_t ws_size,
                              hipStream_t stream) {
  (void)in_sizes; (void)n_in; (void)out_size; (void)ws_size;
  const int* src    = (const int*)d_in[0];
  const int* nidx   = (const int*)d_in[2];
  const int* ncnt   = (const int*)d_in[3];
  const void* tiv   = d_in[4];
  const void* emb   = d_in[5];
  const void* tW    = d_in[6];
  const void* tB    = d_in[7];
  const void* socW  = d_in[8];
  const void* socb  = d_in[9];
  const void* socg  = d_in[10];
  const void* socbe = d_in[11];
  const void* projW = d_in[12];
  const void* projb = d_in[13];
  const void* Wq    = d_in[14];
  const void* bq    = d_in[15];
  const void* Wk    = d_in[16];
  const void* bk    = d_in[17];
  const void* Wv    = d_in[18];
  const void* bv    = d_in[19];
  const void* Wo    = d_in[20];
  const void* bo    = d_in[21];
  const void* ln1g  = d_in[22];
  const void* ln1b  = d_in[23];
  const void* W1    = d_in[24];
  const void* b1    = d_in[25];
  const void* W2    = d_in[26];
  const void* b2    = d_in[27];
  const void* ln2g  = d_in[28];
  const void* ln2b  = d_in[29];

  const size_t NHS = (size_t)NN * HHH;
  const size_t QKV3 = (size_t)3 * HHH * HHH;
  u16* ws = (u16*)d_ws;
  u16* socWT  = ws;
  u16* projWT = socWT + (size_t)DD * DD;
  u16* WqkvT  = projWT + (size_t)DD * HHH;
  u16* WoT    = WqkvT + (size_t)LLL * QKV3;
  u16* W1T    = WoT + (size_t)LLL * HHH * HHH;
  u16* W2T    = W1T + (size_t)LLL * HHH * PFF;
  u16* Hb     = W2T + (size_t)LLL * HHH * PFF;
  u16* P1     = Hb + NHS;
  u16* P2     = P1 + NHS;
  u16* P3     = P2 + NHS;
  int* flagp  = (int*)(P3 + NHS);
  u16* packb  = (u16*)(flagp + 4);
  u16* X    = P1;
  u16* AGG  = P2;
  u16* SOCP = P3;
  u16* X2   = P2;
  u16* Ob   = (u16*)d_out;
  u16* FFM  = P2;    // per 8192-row chunk: [8192, 2048] = 2*NHS, spans P2+P3 exactly

  k_flag<<<1, 1, 0, stream>>>((const u32*)ln1g, flagp);

  dim3 tb(32, 8);
  k_transpose_f<<<dim3(DD / 32, DD / 32), tb, 0, stream>>>(socW, 0, socWT, DD, DD, flagp);
  k_transpose_f<<<dim3(HHH / 32, DD / 32), tb, 0, stream>>>(projW, 0, projWT, DD, HHH, flagp);
  for (int l = 0; l < LLL; ++l) {
    size_t oHH = (size_t)l * HHH * HHH, oHP = (size_t)l * HHH * PFF;
    u16* wq = WqkvT + (size_t)l * QKV3;
    k_transpose_f<<<dim3(HHH / 32, HHH / 32), tb, 0, stream>>>(Wq, oHH, wq, HHH, HHH, flagp);
    k_transpose_f<<<dim3(HHH / 32, HHH / 32), tb, 0, stream>>>(Wk, oHH, wq + (size_t)HHH * HHH, HHH, HHH, flagp);
    k_transpose_f<<<dim3(HHH / 32, HHH / 32), tb, 0, stream>>>(Wv, oHH, wq + (size_t)2 * HHH * HHH, HHH, HHH, flagp);
    k_transpose_f<<<dim3(HHH / 32, HHH / 32), tb, 0, stream>>>(Wo, oHH, WoT + oHH, HHH, HHH, flagp);
    k_transpose_f<<<dim3(PFF / 32, HHH / 32), tb, 0, stream>>>(W1, oHP, W1T + oHP, HHH, PFF, flagp);
    k_transpose_f<<<dim3(HHH / 32, PFF / 32), tb, 0, stream>>>(W2, oHP, W2T + oHP, PFF, HHH, flagp);
  }
  k_packb<<<dim3((512 + LLL * 4608 + 255) / 256), 256, 0, stream>>>(
      projb, bq, bk, bv, b1, bo, b2, packb, flagp);

  k_embed<<<NN, 256, 0, stream>>>(src, tiv, emb, tW, tB, X, flagp);
  k_agg<<<NN, 256, 0, stream>>>(nidx, ncnt, X, AGG);
  k_gemm128<<<dim3(DD / 128, NN / 128), 256, 0, stream>>>(AGG, socWT, socb, 0, X, SOCP, DD, DD, 0, flagp);
  k_ln_soc<<<NN, 256, 0, stream>>>(SOCP, X, socg, socbe, ncnt, src, X2, d_out, flagp);
  // proj: [16384,256] @ [256,512] -> Hb
  k_gemm256<2><<<dim3(256), 512, 0, stream>>>(X2, projWT, packb, Hb, HHH, DD, 0, 4);

  for (int l = 0; l < LLL; ++l) {
    size_t oHH = (size_t)l * HHH * HHH, oHP = (size_t)l * HHH * PFF;
    u16* lb = packb + 512 + (size_t)l * 4608;
    // fused QKV: [16384,512] @ [512,1536] -> P1 (row stride 1536, spans P1..P3)
    k_gemm256<4><<<dim3(384), 512, 0, stream>>>(Hb, WqkvT + (size_t)l * QKV3, lb, P1, 1536, HHH, 0, 6);
    k_attn_mfma<<<dim3(NHH, BB), 512, 0, stream>>>(P1, P1 + HHH, P1 + 2 * HHH, 3 * HHH, src, Ob);
    // Wo: [16384,512] @ [512,512] -> P1
    k_gemm256<2><<<dim3(256), 512, 0, stream>>>(Ob, WoT + oHH, lb + 3584, P1, HHH, HHH, 0, 4);
    k_ln_add<<<NN, 256, 0, stream>>>(Hb, P1, ln1g, l * HHH, ln1b, l * HHH, Hb, flagp);
    // FF in 2 chunks of 8192 rows: FFM = [8192,2048] fits P2+P3 exactly (NO overflow)
    for (int c = 0; c < 2; ++c) {
      const u16* Asrc = Hb + (size_t)c * 8192 * HHH;
      u16* Cdst = P1 + (size_t)c * 8192 * HHH;
      k_gemm256<4><<<dim3(256), 512, 0, stream>>>(Asrc, W1T + oHP, lb + 1536, FFM, PFF, HHH, 1, 8);
      k_gemm256<2><<<dim3(128), 512, 0, stream>>>(FFM, W2T + oHP, lb + 4096, Cdst, HHH, PFF, 0, 4);
    }
    k_ln_add<<<NN, 256, 0, stream>>>(Hb, P1, ln2g, l * HHH, ln2b, l * HHH, Hb, flagp);
  }
  k_out<<<dim3((unsigned)(NHS / 4 / 256)), 256, 0, stream>>>(Hb, d_out, flagp);
}

// Round 5
// 860.654 us; speedup vs baseline: 1.3970x; 1.0465x over previous
//
#include <hip/hip_runtime.h>

#define BB 32
#define SS 512
#define DD 256
#define HHH 512
#define NHH 8
#define HDD 64
#define PFF 2048
#define LLL 2
#define NN (BB*SS)      /* 16384 tokens */
#define NMAXX 15

typedef unsigned short u16;
typedef unsigned int u32;

typedef __attribute__((ext_vector_type(8))) __bf16 bf16x8;
typedef __attribute__((ext_vector_type(4))) float f32x4;

__device__ __forceinline__ float bf2f(u16 u) {
  union { u32 i; float f; } x; x.i = ((u32)u) << 16; return x.f;
}
__device__ __forceinline__ u16 f2bf(float f) {
  union { float f; u32 i; } x; x.f = f;
  u32 r = x.i + 0x7FFFu + ((x.i >> 16) & 1u);
  return (u16)(r >> 16);
}
// flag==1: inputs/outputs are bf16; flag==0: they are float32
__device__ __forceinline__ float ldf(const void* p, size_t i, int flag) {
  return flag ? bf2f(((const u16*)p)[i]) : ((const float*)p)[i];
}
__device__ __forceinline__ void stf(void* p, size_t i, int flag, float v) {
  if (flag) ((u16*)p)[i] = f2bf(v); else ((float*)p)[i] = v;
}
// async global->LDS, 16B per lane; LDS dest must be wave-uniform base + lane*16
__device__ __forceinline__ void gld16(const u16* g, u16* l) {
  __builtin_amdgcn_global_load_lds(
      (const __attribute__((address_space(1))) u32*)g,
      (__attribute__((address_space(3))) u32*)l, 16, 0, 0);
}

// ---------------- dtype probe: ln1_g[0] == 1.0 ----------------
__global__ void k_flag(const u32* __restrict__ ones, int* __restrict__ flag) {
  *flag = (ones[0] == 0x3F800000u) ? 0 : 1;
}

// ---------------- fused convert + transpose [R,C] -> bf16 [C,R] ----------------
__global__ __launch_bounds__(256) void k_transpose_f(const void* __restrict__ in, size_t ioff,
    u16* __restrict__ out, int R, int C, const int* __restrict__ flagp) {
  __shared__ u16 tile[32][33];
  int flag = *flagp;
  int c0 = blockIdx.x * 32, r0 = blockIdx.y * 32;
  int tx = threadIdx.x, ty = threadIdx.y;  // 32 x 8
  #pragma unroll
  for (int i = 0; i < 4; ++i)
    tile[ty + i*8][tx] = f2bf(ldf(in, ioff + (size_t)(r0 + ty + i*8) * C + c0 + tx, flag));
  __syncthreads();
  #pragma unroll
  for (int i = 0; i < 4; ++i) out[(size_t)(c0 + ty + i*8) * R + r0 + tx] = tile[tx][ty + i*8];
}

// ---------------- pack all biases to bf16 ----------------
// layout: [projb 512][per-layer: bq,bk,bv (1536) | b1 (2048) | bo (512) | b2 (512)]
__global__ __launch_bounds__(256) void k_packb(const void* __restrict__ projb,
    const void* __restrict__ bq, const void* __restrict__ bk, const void* __restrict__ bv,
    const void* __restrict__ b1, const void* __restrict__ bo, const void* __restrict__ b2,
    u16* __restrict__ out, const int* __restrict__ flagp) {
  int flag = *flagp;
  int i = blockIdx.x * 256 + threadIdx.x;
  int tot = 512 + LLL * 4608;
  if (i >= tot) return;
  float v;
  if (i < 512) v = ldf(projb, i, flag);
  else {
    int j = i - 512, l = j / 4608, r = j % 4608;
    if      (r < 512)  v = ldf(bq, (size_t)l * HHH + r, flag);
    else if (r < 1024) v = ldf(bk, (size_t)l * HHH + r - 512, flag);
    else if (r < 1536) v = ldf(bv, (size_t)l * HHH + r - 1024, flag);
    else if (r < 3584) v = ldf(b1, (size_t)l * PFF + r - 1536, flag);
    else if (r < 4096) v = ldf(bo, (size_t)l * HHH + r - 3584, flag);
    else               v = ldf(b2, (size_t)l * HHH + r - 4096, flag);
  }
  out[i] = f2bf(v);
}

// ---------------- PE + time-bias table: pet[s][d] = PE(s,d) + tB[d] ----------------
__global__ __launch_bounds__(256) void k_pe(const void* __restrict__ tB,
    u16* __restrict__ pet, const int* __restrict__ flagp) {
  int flag = *flagp;
  int s = blockIdx.x, d = threadIdx.x;
  int i2 = d & ~1;
  float freq = expf(-0.035977892078031968f * (float)i2);
  float ang = (float)s * freq;
  float v = ((d & 1) ? cosf(ang) : sinf(ang)) + ldf(tB, d, flag);
  pet[(size_t)s * DD + d] = f2bf(v);
}

// ---------------- embedding + PE table + time encoding (no trig) ----------------
__global__ __launch_bounds__(256) void k_embed(const int* __restrict__ src,
    const void* __restrict__ tiv, const void* __restrict__ emb,
    const void* __restrict__ tW, const u16* __restrict__ pet,
    u16* __restrict__ X, const int* __restrict__ flagp) {
  int flag = *flagp;
  int n = blockIdx.x, d = threadIdx.x;
  int s = n & (SS - 1);
  int tok = src[n];
  float v = ldf(emb, (size_t)tok * DD + d, flag);
  v += bf2f(pet[(size_t)s * DD + d]);
  float t = ldf(tiv, n, flag);
  v += t * ldf(tW, d, flag);
  X[(size_t)n * DD + d] = f2bf(v);
}

// ---------------- neighbor mean aggregation ----------------
__global__ __launch_bounds__(256) void k_agg(const int* __restrict__ nidx,
    const int* __restrict__ ncnt, const u16* __restrict__ X, u16* __restrict__ AGG) {
  int n = blockIdx.x, d = threadIdx.x;
  int cnt = ncnt[n];
  float s = 0.f;
  for (int j = 0; j < cnt; ++j) {
    int m = nidx[n * NMAXX + j];
    s += bf2f(X[(size_t)m * DD + d]);
  }
  float div = (float)(cnt > 0 ? cnt : 1);
  AGG[(size_t)n * DD + d] = f2bf(s / div);
}

// ---------------- m97-style bf16 MFMA GEMM (kept for soc, N=256) ----------------
__global__ __launch_bounds__(256) void k_gemm128(const u16* __restrict__ A,
    const u16* __restrict__ BT, const void* __restrict__ bias, int boff,
    const u16* __restrict__ res, u16* __restrict__ C, int N, int K, int relu,
    const int* __restrict__ flagp) {
  __shared__ __align__(16) u16 As[128 * 32];
  __shared__ __align__(16) u16 Bs[128 * 32];
  int n0 = blockIdx.x * 128, m0 = blockIdx.y * 128;
  int t = threadIdx.x;
  int lane = t & 63, w = t >> 6;
  int wm = (w >> 1) * 64, wn = (w & 1) * 64;
  int fr = lane & 15, fq = lane >> 4;
  int srow = t >> 2, sseg = t & 3;

  f32x4 acc[4][4];
  #pragma unroll
  for (int i = 0; i < 4; ++i)
    #pragma unroll
    for (int j = 0; j < 4; ++j) acc[i][j] = (f32x4){0.f, 0.f, 0.f, 0.f};

  const u16* ga = A  + (size_t)(m0 + srow) * K + sseg * 8;
  const u16* gb = BT + (size_t)(n0 + srow) * K + sseg * 8;
  u16* lA = As + srow * 32 + sseg * 8;
  u16* lB = Bs + srow * 32 + sseg * 8;
  const size_t rstride = (size_t)64 * K;

  for (int k0 = 0; k0 < K; k0 += 32) {
    gld16(ga + k0, lA);
    gld16(ga + k0 + rstride, lA + 64 * 32);
    gld16(gb + k0, lB);
    gld16(gb + k0 + rstride, lB + 64 * 32);
    __syncthreads();
    bf16x8 af[4], bf[4];
    #pragma unroll
    for (int i = 0; i < 4; ++i) af[i] = *(const bf16x8*)&As[(wm + i * 16 + fr) * 32 + fq * 8];
    #pragma unroll
    for (int j = 0; j < 4; ++j) bf[j] = *(const bf16x8*)&Bs[(wn + j * 16 + fr) * 32 + fq * 8];
    #pragma unroll
    for (int i = 0; i < 4; ++i)
      #pragma unroll
      for (int j = 0; j < 4; ++j)
        acc[i][j] = __builtin_amdgcn_mfma_f32_16x16x32_bf16(af[i], bf[j], acc[i][j], 0, 0, 0);
    __syncthreads();
  }

  int flag = *flagp;
  #pragma unroll
  for (int j = 0; j < 4; ++j) {
    int col = n0 + wn + j * 16 + fr;
    float bv = bias ? ldf(bias, boff + col, flag) : 0.f;
    #pragma unroll
    for (int i = 0; i < 4; ++i) {
      #pragma unroll
      for (int c = 0; c < 4; ++c) {
        int row = m0 + wm + i * 16 + fq * 4 + c;
        float v = acc[i][j][c] + bv;
        if (res) v += bf2f(res[(size_t)row * N + col]);
        if (relu) v = fmaxf(v, 0.f);
        C[(size_t)row * N + col] = f2bf(v);
      }
    }
  }
}

// ---------------- pipelined 256-row-tile GEMM: BM=256, BN=64*NBF, BK=32 ----------------
// 3 LDS stages; stage tile T+2 while computing tile T; counted vmcnt (T4); XOR-swizzled
// LDS granules (T2, both sides); setprio around MFMA clusters (T5); XCD block swizzle (T1).
template<int NBF>
__global__ __launch_bounds__(512, 2) void k_gemm256(const u16* __restrict__ A,
    const u16* __restrict__ BT, const u16* __restrict__ bias,
    u16* __restrict__ C, int N, int K, int relu, int nbx) {
  constexpr int AG = 1024;                 // A 16B-granules per stage: 256 rows x 4
  constexpr int BG = NBF * 256;            // B granules per stage: 64*NBF rows x 4
  constexpr int STRIDE = (AG + BG) * 8;    // u16 per stage
  constexpr int LPT = 2 + BG / 512;        // gld16 per thread per tile
  __shared__ __align__(16) u16 S[3 * STRIDE];

  int nwg = gridDim.x;
  int id = blockIdx.x;
  int wg = ((nwg & 7) == 0) ? ((id & 7) * (nwg >> 3) + (id >> 3)) : id;
  int bx = wg % nbx, by = wg / nbx;
  int m0 = by * 256, n0 = bx * (64 * NBF);

  int t = threadIdx.x;
  int w = t >> 6, lane = t & 63;
  int fr = lane & 15, fq = lane >> 4;
  int wm = (w >> 2) * 128, wn = (w & 3) * (16 * NBF);
  // frag-read granule: fq ^ (row&3) ^ ((row>>2)&3), row = base16 + fr -> lane-constant
  int gsw8 = (fq ^ (fr & 3) ^ ((fr >> 2) & 3)) * 8;

  // staging: thread t covers granule t (and t+512): row = g>>2, seg = g&3
  int arow = t >> 2, aseg = t & 3;
  int asw = aseg ^ (arow & 3) ^ ((arow >> 2) & 3);   // row+128 keeps same swizzle
  const u16* gA  = A  + (size_t)(m0 + arow) * K + asw * 8;
  const u16* gA2 = gA + (size_t)128 * K;
  const u16* gB  = BT + (size_t)(n0 + arow) * K + asw * 8;
  const u16* gB2 = gB + (size_t)128 * K;             // used when NBF==4

  f32x4 acc[8][NBF];
  #pragma unroll
  for (int i = 0; i < 8; ++i)
    #pragma unroll
    for (int j = 0; j < NBF; ++j) acc[i][j] = (f32x4){0.f, 0.f, 0.f, 0.f};

  int NT = K >> 5;

  // prologue: stage tiles 0,1; wait until tile 0 landed (LPT outstanding = tile 1)
  #pragma unroll
  for (int p = 0; p < 2; ++p) {
    gld16(gA  + p * 32, S + p * STRIDE + t * 8);
    gld16(gA2 + p * 32, S + p * STRIDE + (t + 512) * 8);
    gld16(gB  + p * 32, S + p * STRIDE + AG * 8 + t * 8);
    if constexpr (NBF == 4)
      gld16(gB2 + p * 32, S + p * STRIDE + AG * 8 + (t + 512) * 8);
  }
  asm volatile("s_waitcnt vmcnt(%0)" :: "n"(LPT) : "memory");
  __builtin_amdgcn_s_barrier();
  __builtin_amdgcn_sched_barrier(0);

  for (int T = 0; T < NT; ++T) {
    const u16* Sa = S + (T % 3) * STRIDE;
    const u16* Sb = Sa + AG * 8;
    u16* Sn = S + ((T + 2) % 3) * STRIDE;
    int kn = (T + 2) * 32;
    bool st = (T + 2) < NT;

    // phase a: read A-half0 + B frags, stage next A-tile, MFMA rows 0..63
    bf16x8 af[4], bf[NBF];
    #pragma unroll
    for (int i = 0; i < 4; ++i) af[i] = *(const bf16x8*)&Sa[(wm + i * 16 + fr) * 32 + gsw8];
    #pragma unroll
    for (int j = 0; j < NBF; ++j) bf[j] = *(const bf16x8*)&Sb[(wn + j * 16 + fr) * 32 + gsw8];
    if (st) {
      gld16(gA  + kn, Sn + t * 8);
      gld16(gA2 + kn, Sn + (t + 512) * 8);
    }
    __builtin_amdgcn_s_setprio(1);
    #pragma unroll
    for (int i = 0; i < 4; ++i)
      #pragma unroll
      for (int j = 0; j < NBF; ++j)
        acc[i][j] = __builtin_amdgcn_mfma_f32_16x16x32_bf16(af[i], bf[j], acc[i][j], 0, 0, 0);
    __builtin_amdgcn_s_setprio(0);

    // phase b: read A-half1, stage next B-tile, MFMA rows 64..127
    bf16x8 ag[4];
    #pragma unroll
    for (int i = 0; i < 4; ++i) ag[i] = *(const bf16x8*)&Sa[(wm + 64 + i * 16 + fr) * 32 + gsw8];
    if (st) {
      gld16(gB + kn, Sn + AG * 8 + t * 8);
      if constexpr (NBF == 4)
        gld16(gB2 + kn, Sn + AG * 8 + (t + 512) * 8);
    }
    __builtin_amdgcn_s_setprio(1);
    #pragma unroll
    for (int i = 0; i < 4; ++i)
      #pragma unroll
      for (int j = 0; j < NBF; ++j)
        acc[4 + i][j] = __builtin_amdgcn_mfma_f32_16x16x32_bf16(ag[i], bf[j], acc[4 + i][j], 0, 0, 0);
    __builtin_amdgcn_s_setprio(0);

    // tile boundary: drain this wave's ds_reads + counted vmcnt, then barrier.
    if (st) { asm volatile("s_waitcnt vmcnt(%0) lgkmcnt(0)" :: "n"(LPT) : "memory"); }
    else    { asm volatile("s_waitcnt vmcnt(0) lgkmcnt(0)" ::: "memory"); }
    __builtin_amdgcn_s_barrier();
    __builtin_amdgcn_sched_barrier(0);
  }

  #pragma unroll
  for (int j = 0; j < NBF; ++j) {
    int col = n0 + wn + j * 16 + fr;
    float bv = bf2f(bias[col]);
    #pragma unroll
    for (int i = 0; i < 8; ++i) {
      #pragma unroll
      for (int c = 0; c < 4; ++c) {
        int row = m0 + wm + i * 16 + fq * 4 + c;
        float v = acc[i][j][c] + bv;
        if (relu) v = fmaxf(v, 0.f);
        C[(size_t)row * N + col] = f2bf(v);
      }
    }
  }
}

// ---------------- soc LayerNorm(D=256) + relu + select + x += 0.2*soc ----------------
__global__ __launch_bounds__(256) void k_ln_soc(const u16* __restrict__ socp,
    const u16* __restrict__ X, const void* __restrict__ g, const void* __restrict__ beta,
    const int* __restrict__ ncnt, const int* __restrict__ src,
    u16* __restrict__ X2, void* __restrict__ dout, const int* __restrict__ flagp) {
  __shared__ float sred[4];
  int flag = *flagp;
  int n = blockIdx.x, t = threadIdx.x;
  size_t base = (size_t)n * DD;
  float v = bf2f(socp[base + t]);
  float s = v;
  #pragma unroll
  for (int o = 32; o; o >>= 1) s += __shfl_xor(s, o, 64);
  if ((t & 63) == 0) sred[t >> 6] = s;
  __syncthreads();
  float mean = (sred[0] + sred[1] + sred[2] + sred[3]) * (1.f / DD);
  float dv = v - mean;
  float q = dv * dv;
  #pragma unroll
  for (int o = 32; o; o >>= 1) q += __shfl_xor(q, o, 64);
  __syncthreads();
  if ((t & 63) == 0) sred[t >> 6] = q;
  __syncthreads();
  float var = (sred[0] + sred[1] + sred[2] + sred[3]) * (1.f / DD);
  float rs = rsqrtf(var + 1e-5f);
  float soc = fmaxf(dv * rs * ldf(g, t, flag) + ldf(beta, t, flag), 0.f);
  float xv = bf2f(X[base + t]);
  if (ncnt[n] <= 0) soc = xv;
  if (src[n] == 0)  soc = 0.f;
  float ov = xv + 0.2f * soc;
  X2[base + t] = f2bf(ov);
  stf(dout, (size_t)NN * HHH + base + t, flag, ov);
}

// ---------------- LayerNorm(H=512) of (a+b); out bf16, or dout (output dtype) ----------------
__global__ __launch_bounds__(256) void k_ln_add(const u16* __restrict__ a,
    const u16* __restrict__ b, const void* __restrict__ g, int goff,
    const void* __restrict__ bb, int boff, u16* __restrict__ out,
    void* __restrict__ dout, const int* __restrict__ flagp) {
  __shared__ float sred[4];
  int flag = *flagp;
  int row = blockIdx.x, t = threadIdx.x;
  size_t base = (size_t)row * HHH;
  float v0 = bf2f(a[base + t])       + bf2f(b[base + t]);
  float v1 = bf2f(a[base + 256 + t]) + bf2f(b[base + 256 + t]);
  float s = v0 + v1;
  #pragma unroll
  for (int o = 32; o; o >>= 1) s += __shfl_xor(s, o, 64);
  if ((t & 63) == 0) sred[t >> 6] = s;
  __syncthreads();
  float mean = (sred[0] + sred[1] + sred[2] + sred[3]) * (1.f / HHH);
  float d0 = v0 - mean, d1 = v1 - mean;
  float q = d0 * d0 + d1 * d1;
  #pragma unroll
  for (int o = 32; o; o >>= 1) q += __shfl_xor(q, o, 64);
  __syncthreads();
  if ((t & 63) == 0) sred[t >> 6] = q;
  __syncthreads();
  float var = (sred[0] + sred[1] + sred[2] + sred[3]) * (1.f / HHH);
  float rs = rsqrtf(var + 1e-5f);
  float o0 = d0 * rs * ldf(g, goff + t, flag)       + ldf(bb, boff + t, flag);
  float o1 = d1 * rs * ldf(g, goff + 256 + t, flag) + ldf(bb, boff + 256 + t, flag);
  if (dout) {
    stf(dout, base + t, flag, o0);
    stf(dout, base + 256 + t, flag, o1);
  } else {
    out[base + t]       = f2bf(o0);
    out[base + 256 + t] = f2bf(o1);
  }
}

// ---------------- MFMA attention: one block per (head, batch); Q/K/V strided (ld) ----------------
__global__ __launch_bounds__(512, 2) void k_attn_mfma(const u16* __restrict__ Q,
    const u16* __restrict__ Kb, const u16* __restrict__ Vb, int ld,
    const int* __restrict__ src, u16* __restrict__ O) {
  __shared__ __align__(16) u16 Ks[512 * 64];
  __shared__ __align__(16) u16 VTs[64 * 512];
  __shared__ __align__(16) u16 Ps[128 * 72];
  __shared__ float maskv[512];
  int h = blockIdx.x, b = blockIdx.y;
  int t = threadIdx.x;
  int w = t >> 6, lane = t & 63;
  int fr = lane & 15, fq = lane >> 4;

  maskv[t] = (src[b * SS + t] != 0) ? 1.f : 0.f;

  #pragma unroll
  for (int i = 0; i < 8; ++i) {
    int off = t + i * 512;
    int row = off >> 3;
    int gs  = (off & 7) ^ (row & 7);
    gld16(Kb + (size_t)(b * SS + row) * ld + h * HDD + gs * 8, Ks + (size_t)off * 8);
  }
  {
    const u16* vsrc = Vb + (size_t)(b * SS + t) * ld + h * HDD;
    int ghi = (t >> 3) & ~7, glo = (t >> 3) & 7, kw = t & 7;
    #pragma unroll
    for (int i = 0; i < 8; ++i) {
      uint4 raw = *(const uint4*)(vsrc + i * 8);
      u16 e[8]; *(uint4*)e = raw;
      #pragma unroll
      for (int jj = 0; jj < 8; ++jj) {
        int d = i * 8 + jj;
        VTs[(size_t)d * 512 + (size_t)((ghi | (glo ^ (d & 7))) * 8 + kw)] = e[jj];
      }
    }
  }
  __syncthreads();

  for (int chunk = 0; chunk < 4; ++chunk) {
    int qb = chunk * 128 + w * 16;
    bf16x8 qf[2];
    #pragma unroll
    for (int kc = 0; kc < 2; ++kc)
      qf[kc] = *(const bf16x8*)&Q[(size_t)(b * SS + qb + fr) * ld + h * HDD + kc * 32 + fq * 8];

    f32x4 sacc[32];
    #pragma unroll
    for (int j = 0; j < 32; ++j) sacc[j] = (f32x4){0.f, 0.f, 0.f, 0.f};

    #pragma unroll
    for (int kt = 0; kt < 32; ++kt) {
      int row = kt * 16 + fr;
      #pragma unroll
      for (int kc = 0; kc < 2; ++kc) {
        bf16x8 kf = *(const bf16x8*)&Ks[(size_t)row * 64 +
            (size_t)(((kc * 4 + fq) ^ (fr & 7)) * 8)];
        sacc[kt] = __builtin_amdgcn_mfma_f32_16x16x32_bf16(qf[kc], kf, sacc[kt], 0, 0, 0);
      }
    }

    #pragma unroll
    for (int j = 0; j < 32; ++j) {
      float mv = maskv[j * 16 + fr];
      #pragma unroll
      for (int c = 0; c < 4; ++c) {
        float v = sacc[j][c] * 0.125f;
        sacc[j][c] = (mv != 0.f) ? v : -1e10f;
      }
    }
    #pragma unroll
    for (int c = 0; c < 4; ++c) {
      float m = -3.0e38f;
      #pragma unroll
      for (int j = 0; j < 32; ++j) m = fmaxf(m, sacc[j][c]);
      #pragma unroll
      for (int o = 1; o < 16; o <<= 1) m = fmaxf(m, __shfl_xor(m, o, 64));
      float s = 0.f;
      #pragma unroll
      for (int j = 0; j < 32; ++j) { float e = __expf(sacc[j][c] - m); sacc[j][c] = e; s += e; }
      #pragma unroll
      for (int o = 1; o < 16; o <<= 1) s += __shfl_xor(s, o, 64);
      float inv = 1.f / s;
      #pragma unroll
      for (int j = 0; j < 32; ++j) sacc[j][c] *= inv;
    }

    f32x4 oacc[4];
    #pragma unroll
    for (int n = 0; n < 4; ++n) oacc[n] = (f32x4){0.f, 0.f, 0.f, 0.f};

    // PV with SWAPPED operands: mfma(VT-row, P-row) computes O^T per block,
    // so output row = d (A rows), col = q (B rows). Identical frag loads; only
    // the C layout transposes -> packed 8B O-stores below.
    #pragma unroll
    for (int seg = 0; seg < 8; ++seg) {
      #pragma unroll
      for (int tt = 0; tt < 4; ++tt)
        #pragma unroll
        for (int c = 0; c < 4; ++c)
          Ps[(size_t)(w * 16 + fq * 4 + c) * 72 + tt * 16 + fr] = f2bf(sacc[seg * 4 + tt][c]);
      #pragma unroll
      for (int kc = 0; kc < 2; ++kc) {
        bf16x8 pa = *(const bf16x8*)&Ps[(size_t)(w * 16 + fr) * 72 + kc * 32 + fq * 8];
        #pragma unroll
        for (int nt = 0; nt < 4; ++nt) {
          bf16x8 bv = *(const bf16x8*)&VTs[(size_t)(nt * 16 + fr) * 512 +
              (size_t)((seg * 8 + ((kc * 4 + fq) ^ (fr & 7))) * 8)];
          oacc[nt] = __builtin_amdgcn_mfma_f32_16x16x32_bf16(bv, pa, oacc[nt], 0, 0, 0);
        }
      }
    }

    // O-write: lane fr owns q = qb + fr; per nt writes 4 contiguous u16 (8B)
    // at d = nt*16 + fq*4 .. +3.
    #pragma unroll
    for (int nt = 0; nt < 4; ++nt) {
      union { u16 e[4]; uint2 v; } pk;
      #pragma unroll
      for (int c = 0; c < 4; ++c) pk.e[c] = f2bf(oacc[nt][c]);
      *(uint2*)&O[(size_t)(b * SS + qb + fr) * HHH + h * HDD + nt * 16 + fq * 4] = pk.v;
    }
  }
}

extern "C" void kernel_launch(void* const* d_in, const int* in_sizes, int n_in,
                              void* d_out, int out_size, void* d_ws, size_t ws_size,
                              hipStream_t stream) {
  (void)in_sizes; (void)n_in; (void)out_size;
  const int* src    = (const int*)d_in[0];
  const int* nidx   = (const int*)d_in[2];
  const int* ncnt   = (const int*)d_in[3];
  const void* tiv   = d_in[4];
  const void* emb   = d_in[5];
  const void* tW    = d_in[6];
  const void* tB    = d_in[7];
  const void* socW  = d_in[8];
  const void* socb  = d_in[9];
  const void* socg  = d_in[10];
  const void* socbe = d_in[11];
  const void* projW = d_in[12];
  const void* projb = d_in[13];
  const void* Wq    = d_in[14];
  const void* bq    = d_in[15];
  const void* Wk    = d_in[16];
  const void* bk    = d_in[17];
  const void* Wv    = d_in[18];
  const void* bv    = d_in[19];
  const void* Wo    = d_in[20];
  const void* bo    = d_in[21];
  const void* ln1g  = d_in[22];
  const void* ln1b  = d_in[23];
  const void* W1    = d_in[24];
  const void* b1    = d_in[25];
  const void* W2    = d_in[26];
  const void* b2    = d_in[27];
  const void* ln2g  = d_in[28];
  const void* ln2b  = d_in[29];

  const size_t NHS = (size_t)NN * HHH;
  const size_t QKV3 = (size_t)3 * HHH * HHH;
  u16* ws = (u16*)d_ws;
  u16* socWT  = ws;
  u16* projWT = socWT + (size_t)DD * DD;
  u16* WqkvT  = projWT + (size_t)DD * HHH;
  u16* WoT    = WqkvT + (size_t)LLL * QKV3;
  u16* W1T    = WoT + (size_t)LLL * HHH * HHH;
  u16* W2T    = W1T + (size_t)LLL * HHH * PFF;
  u16* Hb     = W2T + (size_t)LLL * HHH * PFF;
  u16* P1     = Hb + NHS;
  u16* P2     = P1 + NHS;
  u16* P3     = P2 + NHS;
  int* flagp  = (int*)(P3 + NHS);
  u16* packb  = (u16*)(flagp + 4);
  u16* pet    = packb + 16384;                    // PE table [512,256]
  u16* FFMf   = pet + (size_t)SS * DD;            // full FFM [16384,2048] (if ws allows)
  size_t need_full = (size_t)(FFMf - ws + (size_t)NN * PFF) * 2;
  int fullff = (ws_size >= need_full);

  u16* X    = P1;
  u16* AGG  = P2;
  u16* SOCP = P3;
  u16* X2   = P2;
  u16* Ob   = (u16*)d_out;
  u16* FFMc = P2;    // chunked fallback: [8192,2048] spans P2+P3

  k_flag<<<1, 1, 0, stream>>>((const u32*)ln1g, flagp);

  dim3 tb(32, 8);
  k_transpose_f<<<dim3(DD / 32, DD / 32), tb, 0, stream>>>(socW, 0, socWT, DD, DD, flagp);
  k_transpose_f<<<dim3(HHH / 32, DD / 32), tb, 0, stream>>>(projW, 0, projWT, DD, HHH, flagp);
  for (int l = 0; l < LLL; ++l) {
    size_t oHH = (size_t)l * HHH * HHH, oHP = (size_t)l * HHH * PFF;
    u16* wq = WqkvT + (size_t)l * QKV3;
    k_transpose_f<<<dim3(HHH / 32, HHH / 32), tb, 0, stream>>>(Wq, oHH, wq, HHH, HHH, flagp);
    k_transpose_f<<<dim3(HHH / 32, HHH / 32), tb, 0, stream>>>(Wk, oHH, wq + (size_t)HHH * HHH, HHH, HHH, flagp);
    k_transpose_f<<<dim3(HHH / 32, HHH / 32), tb, 0, stream>>>(Wv, oHH, wq + (size_t)2 * HHH * HHH, HHH, HHH, flagp);
    k_transpose_f<<<dim3(HHH / 32, HHH / 32), tb, 0, stream>>>(Wo, oHH, WoT + oHH, HHH, HHH, flagp);
    k_transpose_f<<<dim3(PFF / 32, HHH / 32), tb, 0, stream>>>(W1, oHP, W1T + oHP, HHH, PFF, flagp);
    k_transpose_f<<<dim3(HHH / 32, PFF / 32), tb, 0, stream>>>(W2, oHP, W2T + oHP, PFF, HHH, flagp);
  }
  k_packb<<<dim3((512 + LLL * 4608 + 255) / 256), 256, 0, stream>>>(
      projb, bq, bk, bv, b1, bo, b2, packb, flagp);
  k_pe<<<SS, 256, 0, stream>>>(tB, pet, flagp);

  k_embed<<<NN, 256, 0, stream>>>(src, tiv, emb, tW, pet, X, flagp);
  k_agg<<<NN, 256, 0, stream>>>(nidx, ncnt, X, AGG);
  k_gemm128<<<dim3(DD / 128, NN / 128), 256, 0, stream>>>(AGG, socWT, socb, 0, X, SOCP, DD, DD, 0, flagp);
  k_ln_soc<<<NN, 256, 0, stream>>>(SOCP, X, socg, socbe, ncnt, src, X2, d_out, flagp);
  // proj: [16384,256] @ [256,512] -> Hb
  k_gemm256<2><<<dim3(256), 512, 0, stream>>>(X2, projWT, packb, Hb, HHH, DD, 0, 4);

  for (int l = 0; l < LLL; ++l) {
    size_t oHH = (size_t)l * HHH * HHH, oHP = (size_t)l * HHH * PFF;
    u16* lb = packb + 512 + (size_t)l * 4608;
    // fused QKV: [16384,512] @ [512,1536] -> P1 (row stride 1536, spans P1..P3)
    k_gemm256<4><<<dim3(384), 512, 0, stream>>>(Hb, WqkvT + (size_t)l * QKV3, lb, P1, 1536, HHH, 0, 6);
    k_attn_mfma<<<dim3(NHH, BB), 512, 0, stream>>>(P1, P1 + HHH, P1 + 2 * HHH, 3 * HHH, src, Ob);
    // Wo: [16384,512] @ [512,512] -> P1
    k_gemm256<2><<<dim3(256), 512, 0, stream>>>(Ob, WoT + oHH, lb + 3584, P1, HHH, HHH, 0, 4);
    k_ln_add<<<NN, 256, 0, stream>>>(Hb, P1, ln1g, l * HHH, ln1b, l * HHH, Hb, nullptr, flagp);
    if (fullff) {
      // FF1: [16384,512]@[512,2048] -> FFMf (grid 512); FF2: -> P1 (grid 256, FULL occupancy)
      k_gemm256<4><<<dim3(512), 512, 0, stream>>>(Hb, W1T + oHP, lb + 1536, FFMf, PFF, HHH, 1, 8);
      k_gemm256<2><<<dim3(256), 512, 0, stream>>>(FFMf, W2T + oHP, lb + 4096, P1, HHH, PFF, 0, 4);
    } else {
      for (int c = 0; c < 2; ++c) {
        const u16* Asrc = Hb + (size_t)c * 8192 * HHH;
        u16* Cdst = P1 + (size_t)c * 8192 * HHH;
        k_gemm256<4><<<dim3(256), 512, 0, stream>>>(Asrc, W1T + oHP, lb + 1536, FFMc, PFF, HHH, 1, 8);
        k_gemm256<2><<<dim3(128), 512, 0, stream>>>(FFMc, W2T + oHP, lb + 4096, Cdst, HHH, PFF, 0, 4);
      }
    }
    // last ln_add writes the output directly (dtype-converted); others write Hb
    void* dd = (l == LLL - 1) ? d_out : nullptr;
    k_ln_add<<<NN, 256, 0, stream>>>(Hb, P1, ln2g, l * HHH, ln2b, l * HHH, Hb, dd, flagp);
  }
}

// Round 6
// 804.495 us; speedup vs baseline: 1.4945x; 1.0698x over previous
//
#include <hip/hip_runtime.h>

#define BB 32
#define SS 512
#define DD 256
#define HHH 512
#define NHH 8
#define HDD 64
#define PFF 2048
#define LLL 2
#define NN (BB*SS)      /* 16384 tokens */
#define NMAXX 15

typedef unsigned short u16;
typedef unsigned int u32;

typedef __attribute__((ext_vector_type(8))) __bf16 bf16x8;
typedef __attribute__((ext_vector_type(4))) float f32x4;

__device__ __forceinline__ float bf2f(u16 u) {
  union { u32 i; float f; } x; x.i = ((u32)u) << 16; return x.f;
}
__device__ __forceinline__ u16 f2bf(float f) {
  union { float f; u32 i; } x; x.f = f;
  u32 r = x.i + 0x7FFFu + ((x.i >> 16) & 1u);
  return (u16)(r >> 16);
}
// flag==1: inputs/outputs are bf16; flag==0: they are float32
__device__ __forceinline__ float ldf(const void* p, size_t i, int flag) {
  return flag ? bf2f(((const u16*)p)[i]) : ((const float*)p)[i];
}
__device__ __forceinline__ void stf(void* p, size_t i, int flag, float v) {
  if (flag) ((u16*)p)[i] = f2bf(v); else ((float*)p)[i] = v;
}
// async global->LDS, 16B per lane; LDS dest must be wave-uniform base + lane*16
__device__ __forceinline__ void gld16(const u16* g, u16* l) {
  __builtin_amdgcn_global_load_lds(
      (const __attribute__((address_space(1))) u32*)g,
      (__attribute__((address_space(3))) u32*)l, 16, 0, 0);
}

// ---------------- dtype probe: ln1_g[0] == 1.0 ----------------
__global__ void k_flag(const u32* __restrict__ ones, int* __restrict__ flag) {
  *flag = (ones[0] == 0x3F800000u) ? 0 : 1;
}

// ---------------- fused convert + transpose [R,C] -> bf16 [C,R] ----------------
__global__ __launch_bounds__(256) void k_transpose_f(const void* __restrict__ in, size_t ioff,
    u16* __restrict__ out, int R, int C, const int* __restrict__ flagp) {
  __shared__ u16 tile[32][33];
  int flag = *flagp;
  int c0 = blockIdx.x * 32, r0 = blockIdx.y * 32;
  int tx = threadIdx.x, ty = threadIdx.y;  // 32 x 8
  #pragma unroll
  for (int i = 0; i < 4; ++i)
    tile[ty + i*8][tx] = f2bf(ldf(in, ioff + (size_t)(r0 + ty + i*8) * C + c0 + tx, flag));
  __syncthreads();
  #pragma unroll
  for (int i = 0; i < 4; ++i) out[(size_t)(c0 + ty + i*8) * R + r0 + tx] = tile[tx][ty + i*8];
}

// ---------------- pack all biases to bf16 ----------------
// layout: [projb 512][per-layer: bq,bk,bv (1536) | b1 (2048) | bo (512) | b2 (512)]
__global__ __launch_bounds__(256) void k_packb(const void* __restrict__ projb,
    const void* __restrict__ bq, const void* __restrict__ bk, const void* __restrict__ bv,
    const void* __restrict__ b1, const void* __restrict__ bo, const void* __restrict__ b2,
    u16* __restrict__ out, const int* __restrict__ flagp) {
  int flag = *flagp;
  int i = blockIdx.x * 256 + threadIdx.x;
  int tot = 512 + LLL * 4608;
  if (i >= tot) return;
  float v;
  if (i < 512) v = ldf(projb, i, flag);
  else {
    int j = i - 512, l = j / 4608, r = j % 4608;
    if      (r < 512)  v = ldf(bq, (size_t)l * HHH + r, flag);
    else if (r < 1024) v = ldf(bk, (size_t)l * HHH + r - 512, flag);
    else if (r < 1536) v = ldf(bv, (size_t)l * HHH + r - 1024, flag);
    else if (r < 3584) v = ldf(b1, (size_t)l * PFF + r - 1536, flag);
    else if (r < 4096) v = ldf(bo, (size_t)l * HHH + r - 3584, flag);
    else               v = ldf(b2, (size_t)l * HHH + r - 4096, flag);
  }
  out[i] = f2bf(v);
}

// ---------------- PE + time-bias table: pet[s][d] = PE(s,d) + tB[d] ----------------
__global__ __launch_bounds__(256) void k_pe(const void* __restrict__ tB,
    u16* __restrict__ pet, const int* __restrict__ flagp) {
  int flag = *flagp;
  int s = blockIdx.x, d = threadIdx.x;
  int i2 = d & ~1;
  float freq = expf(-0.035977892078031968f * (float)i2);
  float ang = (float)s * freq;
  float v = ((d & 1) ? cosf(ang) : sinf(ang)) + ldf(tB, d, flag);
  pet[(size_t)s * DD + d] = f2bf(v);
}

// ---------------- embedding + PE table + time encoding (no trig) ----------------
__global__ __launch_bounds__(256) void k_embed(const int* __restrict__ src,
    const void* __restrict__ tiv, const void* __restrict__ emb,
    const void* __restrict__ tW, const u16* __restrict__ pet,
    u16* __restrict__ X, const int* __restrict__ flagp) {
  int flag = *flagp;
  int n = blockIdx.x, d = threadIdx.x;
  int s = n & (SS - 1);
  int tok = src[n];
  float v = ldf(emb, (size_t)tok * DD + d, flag);
  v += bf2f(pet[(size_t)s * DD + d]);
  float t = ldf(tiv, n, flag);
  v += t * ldf(tW, d, flag);
  X[(size_t)n * DD + d] = f2bf(v);
}

// ---------------- neighbor mean aggregation ----------------
__global__ __launch_bounds__(256) void k_agg(const int* __restrict__ nidx,
    const int* __restrict__ ncnt, const u16* __restrict__ X, u16* __restrict__ AGG) {
  int n = blockIdx.x, d = threadIdx.x;
  int cnt = ncnt[n];
  float s = 0.f;
  for (int j = 0; j < cnt; ++j) {
    int m = nidx[n * NMAXX + j];
    s += bf2f(X[(size_t)m * DD + d]);
  }
  float div = (float)(cnt > 0 ? cnt : 1);
  AGG[(size_t)n * DD + d] = f2bf(s / div);
}

// ---------------- m97-style bf16 MFMA GEMM (kept for soc, N=256) ----------------
__global__ __launch_bounds__(256) void k_gemm128(const u16* __restrict__ A,
    const u16* __restrict__ BT, const void* __restrict__ bias, int boff,
    const u16* __restrict__ res, u16* __restrict__ C, int N, int K, int relu,
    const int* __restrict__ flagp) {
  __shared__ __align__(16) u16 As[128 * 32];
  __shared__ __align__(16) u16 Bs[128 * 32];
  int n0 = blockIdx.x * 128, m0 = blockIdx.y * 128;
  int t = threadIdx.x;
  int lane = t & 63, w = t >> 6;
  int wm = (w >> 1) * 64, wn = (w & 1) * 64;
  int fr = lane & 15, fq = lane >> 4;
  int srow = t >> 2, sseg = t & 3;

  f32x4 acc[4][4];
  #pragma unroll
  for (int i = 0; i < 4; ++i)
    #pragma unroll
    for (int j = 0; j < 4; ++j) acc[i][j] = (f32x4){0.f, 0.f, 0.f, 0.f};

  const u16* ga = A  + (size_t)(m0 + srow) * K + sseg * 8;
  const u16* gb = BT + (size_t)(n0 + srow) * K + sseg * 8;
  u16* lA = As + srow * 32 + sseg * 8;
  u16* lB = Bs + srow * 32 + sseg * 8;
  const size_t rstride = (size_t)64 * K;

  for (int k0 = 0; k0 < K; k0 += 32) {
    gld16(ga + k0, lA);
    gld16(ga + k0 + rstride, lA + 64 * 32);
    gld16(gb + k0, lB);
    gld16(gb + k0 + rstride, lB + 64 * 32);
    __syncthreads();
    bf16x8 af[4], bf[4];
    #pragma unroll
    for (int i = 0; i < 4; ++i) af[i] = *(const bf16x8*)&As[(wm + i * 16 + fr) * 32 + fq * 8];
    #pragma unroll
    for (int j = 0; j < 4; ++j) bf[j] = *(const bf16x8*)&Bs[(wn + j * 16 + fr) * 32 + fq * 8];
    #pragma unroll
    for (int i = 0; i < 4; ++i)
      #pragma unroll
      for (int j = 0; j < 4; ++j)
        acc[i][j] = __builtin_amdgcn_mfma_f32_16x16x32_bf16(af[i], bf[j], acc[i][j], 0, 0, 0);
    __syncthreads();
  }

  int flag = *flagp;
  #pragma unroll
  for (int j = 0; j < 4; ++j) {
    int col = n0 + wn + j * 16 + fr;
    float bv = bias ? ldf(bias, boff + col, flag) : 0.f;
    #pragma unroll
    for (int i = 0; i < 4; ++i) {
      #pragma unroll
      for (int c = 0; c < 4; ++c) {
        int row = m0 + wm + i * 16 + fq * 4 + c;
        float v = acc[i][j][c] + bv;
        if (res) v += bf2f(res[(size_t)row * N + col]);
        if (relu) v = fmaxf(v, 0.f);
        C[(size_t)row * N + col] = f2bf(v);
      }
    }
  }
}

// ---------------- pipelined 256-row-tile GEMM: BM=256, BN=64*NBF, BK=32 ----------------
// 3 LDS stages; stage tile T+2 while computing tile T; counted vmcnt (T4); XOR-swizzled
// LDS granules (T2, both sides); setprio around MFMA clusters (T5); XCD block swizzle (T1).
// Epilogue stores ROW-MAJOR (i,c outer, j inner): per row, the wave's 32B segments for all
// j land in adjacent instructions -> write-combine into full lines (FF1 was 2.5x W-amplified).
template<int NBF>
__global__ __launch_bounds__(512, 2) void k_gemm256(const u16* __restrict__ A,
    const u16* __restrict__ BT, const u16* __restrict__ bias,
    u16* __restrict__ C, int N, int K, int relu, int nbx) {
  constexpr int AG = 1024;                 // A 16B-granules per stage: 256 rows x 4
  constexpr int BG = NBF * 256;            // B granules per stage: 64*NBF rows x 4
  constexpr int STRIDE = (AG + BG) * 8;    // u16 per stage
  constexpr int LPT = 2 + BG / 512;        // gld16 per thread per tile
  __shared__ __align__(16) u16 S[3 * STRIDE];

  int nwg = gridDim.x;
  int id = blockIdx.x;
  int wg = ((nwg & 7) == 0) ? ((id & 7) * (nwg >> 3) + (id >> 3)) : id;
  int bx = wg % nbx, by = wg / nbx;
  int m0 = by * 256, n0 = bx * (64 * NBF);

  int t = threadIdx.x;
  int w = t >> 6, lane = t & 63;
  int fr = lane & 15, fq = lane >> 4;
  int wm = (w >> 2) * 128, wn = (w & 3) * (16 * NBF);
  // frag-read granule: fq ^ (row&3) ^ ((row>>2)&3), row = base16 + fr -> lane-constant
  int gsw8 = (fq ^ (fr & 3) ^ ((fr >> 2) & 3)) * 8;

  // staging: thread t covers granule t (and t+512): row = g>>2, seg = g&3
  int arow = t >> 2, aseg = t & 3;
  int asw = aseg ^ (arow & 3) ^ ((arow >> 2) & 3);   // row+128 keeps same swizzle
  const u16* gA  = A  + (size_t)(m0 + arow) * K + asw * 8;
  const u16* gA2 = gA + (size_t)128 * K;
  const u16* gB  = BT + (size_t)(n0 + arow) * K + asw * 8;
  const u16* gB2 = gB + (size_t)128 * K;             // used when NBF==4

  f32x4 acc[8][NBF];
  #pragma unroll
  for (int i = 0; i < 8; ++i)
    #pragma unroll
    for (int j = 0; j < NBF; ++j) acc[i][j] = (f32x4){0.f, 0.f, 0.f, 0.f};

  int NT = K >> 5;

  // prologue: stage tiles 0,1; wait until tile 0 landed (LPT outstanding = tile 1)
  #pragma unroll
  for (int p = 0; p < 2; ++p) {
    gld16(gA  + p * 32, S + p * STRIDE + t * 8);
    gld16(gA2 + p * 32, S + p * STRIDE + (t + 512) * 8);
    gld16(gB  + p * 32, S + p * STRIDE + AG * 8 + t * 8);
    if constexpr (NBF == 4)
      gld16(gB2 + p * 32, S + p * STRIDE + AG * 8 + (t + 512) * 8);
  }
  asm volatile("s_waitcnt vmcnt(%0)" :: "n"(LPT) : "memory");
  __builtin_amdgcn_s_barrier();
  __builtin_amdgcn_sched_barrier(0);

  for (int T = 0; T < NT; ++T) {
    const u16* Sa = S + (T % 3) * STRIDE;
    const u16* Sb = Sa + AG * 8;
    u16* Sn = S + ((T + 2) % 3) * STRIDE;
    int kn = (T + 2) * 32;
    bool st = (T + 2) < NT;

    // phase a: read A-half0 + B frags, stage next A-tile, MFMA rows 0..63
    bf16x8 af[4], bf[NBF];
    #pragma unroll
    for (int i = 0; i < 4; ++i) af[i] = *(const bf16x8*)&Sa[(wm + i * 16 + fr) * 32 + gsw8];
    #pragma unroll
    for (int j = 0; j < NBF; ++j) bf[j] = *(const bf16x8*)&Sb[(wn + j * 16 + fr) * 32 + gsw8];
    if (st) {
      gld16(gA  + kn, Sn + t * 8);
      gld16(gA2 + kn, Sn + (t + 512) * 8);
    }
    __builtin_amdgcn_s_setprio(1);
    #pragma unroll
    for (int i = 0; i < 4; ++i)
      #pragma unroll
      for (int j = 0; j < NBF; ++j)
        acc[i][j] = __builtin_amdgcn_mfma_f32_16x16x32_bf16(af[i], bf[j], acc[i][j], 0, 0, 0);
    __builtin_amdgcn_s_setprio(0);

    // phase b: read A-half1, stage next B-tile, MFMA rows 64..127
    bf16x8 ag[4];
    #pragma unroll
    for (int i = 0; i < 4; ++i) ag[i] = *(const bf16x8*)&Sa[(wm + 64 + i * 16 + fr) * 32 + gsw8];
    if (st) {
      gld16(gB + kn, Sn + AG * 8 + t * 8);
      if constexpr (NBF == 4)
        gld16(gB2 + kn, Sn + AG * 8 + (t + 512) * 8);
    }
    __builtin_amdgcn_s_setprio(1);
    #pragma unroll
    for (int i = 0; i < 4; ++i)
      #pragma unroll
      for (int j = 0; j < NBF; ++j)
        acc[4 + i][j] = __builtin_amdgcn_mfma_f32_16x16x32_bf16(ag[i], bf[j], acc[4 + i][j], 0, 0, 0);
    __builtin_amdgcn_s_setprio(0);

    // tile boundary: drain this wave's ds_reads + counted vmcnt, then barrier.
    if (st) { asm volatile("s_waitcnt vmcnt(%0) lgkmcnt(0)" :: "n"(LPT) : "memory"); }
    else    { asm volatile("s_waitcnt vmcnt(0) lgkmcnt(0)" ::: "memory"); }
    __builtin_amdgcn_s_barrier();
    __builtin_amdgcn_sched_barrier(0);
  }

  // epilogue: row-major store order for write combining
  float bvj[NBF];
  #pragma unroll
  for (int j = 0; j < NBF; ++j) bvj[j] = bf2f(bias[n0 + wn + j * 16 + fr]);
  #pragma unroll
  for (int i = 0; i < 8; ++i) {
    #pragma unroll
    for (int c = 0; c < 4; ++c) {
      size_t rowb = (size_t)(m0 + wm + i * 16 + fq * 4 + c) * N;
      #pragma unroll
      for (int j = 0; j < NBF; ++j) {
        int col = n0 + wn + j * 16 + fr;
        float v = acc[i][j][c] + bvj[j];
        if (relu) v = fmaxf(v, 0.f);
        C[rowb + col] = f2bf(v);
      }
    }
  }
}

// ---------------- soc LayerNorm(D=256) + relu + select + x += 0.2*soc ----------------
__global__ __launch_bounds__(256) void k_ln_soc(const u16* __restrict__ socp,
    const u16* __restrict__ X, const void* __restrict__ g, const void* __restrict__ beta,
    const int* __restrict__ ncnt, const int* __restrict__ src,
    u16* __restrict__ X2, void* __restrict__ dout, const int* __restrict__ flagp) {
  __shared__ float sred[4];
  int flag = *flagp;
  int n = blockIdx.x, t = threadIdx.x;
  size_t base = (size_t)n * DD;
  float v = bf2f(socp[base + t]);
  float s = v;
  #pragma unroll
  for (int o = 32; o; o >>= 1) s += __shfl_xor(s, o, 64);
  if ((t & 63) == 0) sred[t >> 6] = s;
  __syncthreads();
  float mean = (sred[0] + sred[1] + sred[2] + sred[3]) * (1.f / DD);
  float dv = v - mean;
  float q = dv * dv;
  #pragma unroll
  for (int o = 32; o; o >>= 1) q += __shfl_xor(q, o, 64);
  __syncthreads();
  if ((t & 63) == 0) sred[t >> 6] = q;
  __syncthreads();
  float var = (sred[0] + sred[1] + sred[2] + sred[3]) * (1.f / DD);
  float rs = rsqrtf(var + 1e-5f);
  float soc = fmaxf(dv * rs * ldf(g, t, flag) + ldf(beta, t, flag), 0.f);
  float xv = bf2f(X[base + t]);
  if (ncnt[n] <= 0) soc = xv;
  if (src[n] == 0)  soc = 0.f;
  float ov = xv + 0.2f * soc;
  X2[base + t] = f2bf(ov);
  stf(dout, (size_t)NN * HHH + base + t, flag, ov);
}

// ---------------- LayerNorm(H=512) of (a+b); out bf16, or dout (output dtype) ----------------
__global__ __launch_bounds__(256) void k_ln_add(const u16* __restrict__ a,
    const u16* __restrict__ b, const void* __restrict__ g, int goff,
    const void* __restrict__ bb, int boff, u16* __restrict__ out,
    void* __restrict__ dout, const int* __restrict__ flagp) {
  __shared__ float sred[4];
  int flag = *flagp;
  int row = blockIdx.x, t = threadIdx.x;
  size_t base = (size_t)row * HHH;
  float v0 = bf2f(a[base + t])       + bf2f(b[base + t]);
  float v1 = bf2f(a[base + 256 + t]) + bf2f(b[base + 256 + t]);
  float s = v0 + v1;
  #pragma unroll
  for (int o = 32; o; o >>= 1) s += __shfl_xor(s, o, 64);
  if ((t & 63) == 0) sred[t >> 6] = s;
  __syncthreads();
  float mean = (sred[0] + sred[1] + sred[2] + sred[3]) * (1.f / HHH);
  float d0 = v0 - mean, d1 = v1 - mean;
  float q = d0 * d0 + d1 * d1;
  #pragma unroll
  for (int o = 32; o; o >>= 1) q += __shfl_xor(q, o, 64);
  __syncthreads();
  if ((t & 63) == 0) sred[t >> 6] = q;
  __syncthreads();
  float var = (sred[0] + sred[1] + sred[2] + sred[3]) * (1.f / HHH);
  float rs = rsqrtf(var + 1e-5f);
  float o0 = d0 * rs * ldf(g, goff + t, flag)       + ldf(bb, boff + t, flag);
  float o1 = d1 * rs * ldf(g, goff + 256 + t, flag) + ldf(bb, boff + 256 + t, flag);
  if (dout) {
    stf(dout, base + t, flag, o0);
    stf(dout, base + 256 + t, flag, o1);
  } else {
    out[base + t]       = f2bf(o0);
    out[base + 256 + t] = f2bf(o1);
  }
}

// ---------------- MFMA attention: one block per (head, batch); Q/K/V strided (ld) ----------------
// (PV layout reverted to the R4-measured 62us form: mfma(pa, bv), scalar O-stores.)
__global__ __launch_bounds__(512, 2) void k_attn_mfma(const u16* __restrict__ Q,
    const u16* __restrict__ Kb, const u16* __restrict__ Vb, int ld,
    const int* __restrict__ src, u16* __restrict__ O) {
  __shared__ __align__(16) u16 Ks[512 * 64];
  __shared__ __align__(16) u16 VTs[64 * 512];
  __shared__ __align__(16) u16 Ps[128 * 72];
  __shared__ float maskv[512];
  int h = blockIdx.x, b = blockIdx.y;
  int t = threadIdx.x;
  int w = t >> 6, lane = t & 63;
  int fr = lane & 15, fq = lane >> 4;

  maskv[t] = (src[b * SS + t] != 0) ? 1.f : 0.f;

  #pragma unroll
  for (int i = 0; i < 8; ++i) {
    int off = t + i * 512;
    int row = off >> 3;
    int gs  = (off & 7) ^ (row & 7);
    gld16(Kb + (size_t)(b * SS + row) * ld + h * HDD + gs * 8, Ks + (size_t)off * 8);
  }
  {
    const u16* vsrc = Vb + (size_t)(b * SS + t) * ld + h * HDD;
    int ghi = (t >> 3) & ~7, glo = (t >> 3) & 7, kw = t & 7;
    #pragma unroll
    for (int i = 0; i < 8; ++i) {
      uint4 raw = *(const uint4*)(vsrc + i * 8);
      u16 e[8]; *(uint4*)e = raw;
      #pragma unroll
      for (int jj = 0; jj < 8; ++jj) {
        int d = i * 8 + jj;
        VTs[(size_t)d * 512 + (size_t)((ghi | (glo ^ (d & 7))) * 8 + kw)] = e[jj];
      }
    }
  }
  __syncthreads();

  for (int chunk = 0; chunk < 4; ++chunk) {
    int qb = chunk * 128 + w * 16;
    bf16x8 qf[2];
    #pragma unroll
    for (int kc = 0; kc < 2; ++kc)
      qf[kc] = *(const bf16x8*)&Q[(size_t)(b * SS + qb + fr) * ld + h * HDD + kc * 32 + fq * 8];

    f32x4 sacc[32];
    #pragma unroll
    for (int j = 0; j < 32; ++j) sacc[j] = (f32x4){0.f, 0.f, 0.f, 0.f};

    #pragma unroll
    for (int kt = 0; kt < 32; ++kt) {
      int row = kt * 16 + fr;
      #pragma unroll
      for (int kc = 0; kc < 2; ++kc) {
        bf16x8 kf = *(const bf16x8*)&Ks[(size_t)row * 64 +
            (size_t)(((kc * 4 + fq) ^ (fr & 7)) * 8)];
        sacc[kt] = __builtin_amdgcn_mfma_f32_16x16x32_bf16(qf[kc], kf, sacc[kt], 0, 0, 0);
      }
    }

    #pragma unroll
    for (int j = 0; j < 32; ++j) {
      float mv = maskv[j * 16 + fr];
      #pragma unroll
      for (int c = 0; c < 4; ++c) {
        float v = sacc[j][c] * 0.125f;
        sacc[j][c] = (mv != 0.f) ? v : -1e10f;
      }
    }
    #pragma unroll
    for (int c = 0; c < 4; ++c) {
      float m = -3.0e38f;
      #pragma unroll
      for (int j = 0; j < 32; ++j) m = fmaxf(m, sacc[j][c]);
      #pragma unroll
      for (int o = 1; o < 16; o <<= 1) m = fmaxf(m, __shfl_xor(m, o, 64));
      float s = 0.f;
      #pragma unroll
      for (int j = 0; j < 32; ++j) { float e = __expf(sacc[j][c] - m); sacc[j][c] = e; s += e; }
      #pragma unroll
      for (int o = 1; o < 16; o <<= 1) s += __shfl_xor(s, o, 64);
      float inv = 1.f / s;
      #pragma unroll
      for (int j = 0; j < 32; ++j) sacc[j][c] *= inv;
    }

    f32x4 oacc[4];
    #pragma unroll
    for (int n = 0; n < 4; ++n) oacc[n] = (f32x4){0.f, 0.f, 0.f, 0.f};

    #pragma unroll
    for (int seg = 0; seg < 8; ++seg) {
      #pragma unroll
      for (int tt = 0; tt < 4; ++tt)
        #pragma unroll
        for (int c = 0; c < 4; ++c)
          Ps[(size_t)(w * 16 + fq * 4 + c) * 72 + tt * 16 + fr] = f2bf(sacc[seg * 4 + tt][c]);
      #pragma unroll
      for (int kc = 0; kc < 2; ++kc) {
        bf16x8 pa = *(const bf16x8*)&Ps[(size_t)(w * 16 + fr) * 72 + kc * 32 + fq * 8];
        #pragma unroll
        for (int nt = 0; nt < 4; ++nt) {
          bf16x8 bv = *(const bf16x8*)&VTs[(size_t)(nt * 16 + fr) * 512 +
              (size_t)((seg * 8 + ((kc * 4 + fq) ^ (fr & 7))) * 8)];
          oacc[nt] = __builtin_amdgcn_mfma_f32_16x16x32_bf16(pa, bv, oacc[nt], 0, 0, 0);
        }
      }
    }

    #pragma unroll
    for (int nt = 0; nt < 4; ++nt)
      #pragma unroll
      for (int c = 0; c < 4; ++c)
        O[(size_t)(b * SS + qb + fq * 4 + c) * HHH + h * HDD + nt * 16 + fr] = f2bf(oacc[nt][c]);
  }
}

extern "C" void kernel_launch(void* const* d_in, const int* in_sizes, int n_in,
                              void* d_out, int out_size, void* d_ws, size_t ws_size,
                              hipStream_t stream) {
  (void)in_sizes; (void)n_in; (void)out_size;
  const int* src    = (const int*)d_in[0];
  const int* nidx   = (const int*)d_in[2];
  const int* ncnt   = (const int*)d_in[3];
  const void* tiv   = d_in[4];
  const void* emb   = d_in[5];
  const void* tW    = d_in[6];
  const void* tB    = d_in[7];
  const void* socW  = d_in[8];
  const void* socb  = d_in[9];
  const void* socg  = d_in[10];
  const void* socbe = d_in[11];
  const void* projW = d_in[12];
  const void* projb = d_in[13];
  const void* Wq    = d_in[14];
  const void* bq    = d_in[15];
  const void* Wk    = d_in[16];
  const void* bk    = d_in[17];
  const void* Wv    = d_in[18];
  const void* bv    = d_in[19];
  const void* Wo    = d_in[20];
  const void* bo    = d_in[21];
  const void* ln1g  = d_in[22];
  const void* ln1b  = d_in[23];
  const void* W1    = d_in[24];
  const void* b1    = d_in[25];
  const void* W2    = d_in[26];
  const void* b2    = d_in[27];
  const void* ln2g  = d_in[28];
  const void* ln2b  = d_in[29];

  const size_t NHS = (size_t)NN * HHH;
  const size_t QKV3 = (size_t)3 * HHH * HHH;
  u16* ws = (u16*)d_ws;
  u16* socWT  = ws;
  u16* projWT = socWT + (size_t)DD * DD;
  u16* WqkvT  = projWT + (size_t)DD * HHH;
  u16* WoT    = WqkvT + (size_t)LLL * QKV3;
  u16* W1T    = WoT + (size_t)LLL * HHH * HHH;
  u16* W2T    = W1T + (size_t)LLL * HHH * PFF;
  u16* Hb     = W2T + (size_t)LLL * HHH * PFF;
  u16* P1     = Hb + NHS;
  u16* P2     = P1 + NHS;
  u16* P3     = P2 + NHS;
  int* flagp  = (int*)(P3 + NHS);
  u16* packb  = (u16*)(flagp + 4);
  u16* pet    = packb + 16384;                    // PE table [512,256]
  u16* FFMf   = pet + (size_t)SS * DD;            // full FFM [16384,2048] (if ws allows)
  size_t need_full = (size_t)(FFMf - ws + (size_t)NN * PFF) * 2;
  int fullff = (ws_size >= need_full);

  u16* X    = P1;
  u16* AGG  = P2;
  u16* SOCP = P3;
  u16* X2   = P2;
  u16* Ob   = (u16*)d_out;
  u16* FFMc = P2;    // chunked fallback: [8192,2048] spans P2+P3

  k_flag<<<1, 1, 0, stream>>>((const u32*)ln1g, flagp);

  dim3 tb(32, 8);
  k_transpose_f<<<dim3(DD / 32, DD / 32), tb, 0, stream>>>(socW, 0, socWT, DD, DD, flagp);
  k_transpose_f<<<dim3(HHH / 32, DD / 32), tb, 0, stream>>>(projW, 0, projWT, DD, HHH, flagp);
  for (int l = 0; l < LLL; ++l) {
    size_t oHH = (size_t)l * HHH * HHH, oHP = (size_t)l * HHH * PFF;
    u16* wq = WqkvT + (size_t)l * QKV3;
    k_transpose_f<<<dim3(HHH / 32, HHH / 32), tb, 0, stream>>>(Wq, oHH, wq, HHH, HHH, flagp);
    k_transpose_f<<<dim3(HHH / 32, HHH / 32), tb, 0, stream>>>(Wk, oHH, wq + (size_t)HHH * HHH, HHH, HHH, flagp);
    k_transpose_f<<<dim3(HHH / 32, HHH / 32), tb, 0, stream>>>(Wv, oHH, wq + (size_t)2 * HHH * HHH, HHH, HHH, flagp);
    k_transpose_f<<<dim3(HHH / 32, HHH / 32), tb, 0, stream>>>(Wo, oHH, WoT + oHH, HHH, HHH, flagp);
    k_transpose_f<<<dim3(PFF / 32, HHH / 32), tb, 0, stream>>>(W1, oHP, W1T + oHP, HHH, PFF, flagp);
    k_transpose_f<<<dim3(HHH / 32, PFF / 32), tb, 0, stream>>>(W2, oHP, W2T + oHP, PFF, HHH, flagp);
  }
  k_packb<<<dim3((512 + LLL * 4608 + 255) / 256), 256, 0, stream>>>(
      projb, bq, bk, bv, b1, bo, b2, packb, flagp);
  k_pe<<<SS, 256, 0, stream>>>(tB, pet, flagp);

  k_embed<<<NN, 256, 0, stream>>>(src, tiv, emb, tW, pet, X, flagp);
  k_agg<<<NN, 256, 0, stream>>>(nidx, ncnt, X, AGG);
  k_gemm128<<<dim3(DD / 128, NN / 128), 256, 0, stream>>>(AGG, socWT, socb, 0, X, SOCP, DD, DD, 0, flagp);
  k_ln_soc<<<NN, 256, 0, stream>>>(SOCP, X, socg, socbe, ncnt, src, X2, d_out, flagp);
  // proj: [16384,256] @ [256,512] -> Hb
  k_gemm256<2><<<dim3(256), 512, 0, stream>>>(X2, projWT, packb, Hb, HHH, DD, 0, 4);

  for (int l = 0; l < LLL; ++l) {
    size_t oHH = (size_t)l * HHH * HHH, oHP = (size_t)l * HHH * PFF;
    u16* lb = packb + 512 + (size_t)l * 4608;
    // fused QKV: [16384,512] @ [512,1536] -> P1 (row stride 1536, spans P1..P3)
    k_gemm256<4><<<dim3(384), 512, 0, stream>>>(Hb, WqkvT + (size_t)l * QKV3, lb, P1, 1536, HHH, 0, 6);
    k_attn_mfma<<<dim3(NHH, BB), 512, 0, stream>>>(P1, P1 + HHH, P1 + 2 * HHH, 3 * HHH, src, Ob);
    // Wo: [16384,512] @ [512,512] -> P1
    k_gemm256<2><<<dim3(256), 512, 0, stream>>>(Ob, WoT + oHH, lb + 3584, P1, HHH, HHH, 0, 4);
    k_ln_add<<<NN, 256, 0, stream>>>(Hb, P1, ln1g, l * HHH, ln1b, l * HHH, Hb, nullptr, flagp);
    if (fullff) {
      // FF1: [16384,512]@[512,2048] -> FFMf (grid 512); FF2: -> P1 (grid 256, FULL occupancy)
      k_gemm256<4><<<dim3(512), 512, 0, stream>>>(Hb, W1T + oHP, lb + 1536, FFMf, PFF, HHH, 1, 8);
      k_gemm256<2><<<dim3(256), 512, 0, stream>>>(FFMf, W2T + oHP, lb + 4096, P1, HHH, PFF, 0, 4);
    } else {
      for (int c = 0; c < 2; ++c) {
        const u16* Asrc = Hb + (size_t)c * 8192 * HHH;
        u16* Cdst = P1 + (size_t)c * 8192 * HHH;
        k_gemm256<4><<<dim3(256), 512, 0, stream>>>(Asrc, W1T + oHP, lb + 1536, FFMc, PFF, HHH, 1, 8);
        k_gemm256<2><<<dim3(128), 512, 0, stream>>>(FFMc, W2T + oHP, lb + 4096, Cdst, HHH, PFF, 0, 4);
      }
    }
    // last ln_add writes the output directly (dtype-converted); others write Hb
    void* dd = (l == LLL - 1) ? d_out : nullptr;
    k_ln_add<<<NN, 256, 0, stream>>>(Hb, P1, ln2g, l * HHH, ln2b, l * HHH, Hb, dd, flagp);
  }
}